// Round 5
// baseline (324.457 us; speedup 1.0000x reference)
//
#include <hip/hip_runtime.h>
#include <math.h>

#define NFEAT 512
#define NHID  128
#define NCLASS 16
#define SCAN_BS 512
#define AGG_BLOCKS 2048   // multiple of 8; slice = blockIdx & 7

typedef __attribute__((ext_vector_type(8))) short short8;
typedef __attribute__((ext_vector_type(4))) float f32x4;

static __device__ __forceinline__ ushort f2b(float f) {
    union { float f; uint u; } v; v.f = f;
    uint r = v.u + 0x7FFFu + ((v.u >> 16) & 1u);   // round-to-nearest-even
    return (ushort)(r >> 16);
}
static __device__ __forceinline__ float b2f(uint bits) {
    union { uint u; float f; } v; v.u = bits << 16; return v.f;
}

// ---------------- CSR build ----------------

__global__ void k_init_deg(int* __restrict__ deg, int n) {
    int i = blockIdx.x * blockDim.x + threadIdx.x;
    if (i < n) deg[i] = 1;  // self-loop
}

__global__ void k_count(const int* __restrict__ dst, int e, int* __restrict__ deg) {
    int i = blockIdx.x * blockDim.x + threadIdx.x;
    if (i < e) atomicAdd(&deg[dst[i]], 1);
}

__global__ void k_dinv(const int* __restrict__ deg, float* __restrict__ dinv,
                       int* __restrict__ cursor, int n) {
    int i = blockIdx.x * blockDim.x + threadIdx.x;
    if (i < n) {
        dinv[i] = rsqrtf((float)deg[i]);
        cursor[i] = 0;
    }
}

__global__ void k_scan1(const int* __restrict__ deg, int* __restrict__ offs,
                        int* __restrict__ bsum, int n) {
    __shared__ int s[SCAN_BS];
    int t = threadIdx.x;
    int i = blockIdx.x * SCAN_BS + t;
    int v = (i < n) ? deg[i] : 0;
    s[t] = v;
    for (int off = 1; off < SCAN_BS; off <<= 1) {
        __syncthreads();
        int x = (t >= off) ? s[t - off] : 0;
        __syncthreads();
        s[t] += x;
    }
    __syncthreads();
    if (i < n) offs[i] = s[t] - v;
    if (t == SCAN_BS - 1) bsum[blockIdx.x] = s[t];
}

__global__ void k_scan2(int* __restrict__ bsum, int* __restrict__ offs, int nb, int n) {
    if (threadIdx.x == 0 && blockIdx.x == 0) {
        int run = 0;
        for (int b = 0; b < nb; b++) { int x = bsum[b]; bsum[b] = run; run += x; }
        offs[n] = run;
    }
}

__global__ void k_scan3(int* __restrict__ offs, const int* __restrict__ bsum, int n) {
    int i = blockIdx.x * SCAN_BS + threadIdx.x;
    if (i < n) offs[i] += bsum[blockIdx.x];
}

__global__ void k_fill_edges(const int* __restrict__ src, const int* __restrict__ dst, int e,
                             const int* __restrict__ offs, int* __restrict__ cursor,
                             ushort* __restrict__ col16) {
    int i = blockIdx.x * blockDim.x + threadIdx.x;
    if (i < e) {
        int d = dst[i];
        int p = atomicAdd(&cursor[d], 1);
        col16[offs[d] + p] = (ushort)src[i];
    }
}

__global__ void k_fill_self(const int* __restrict__ offs, int* __restrict__ cursor,
                            ushort* __restrict__ col16, int n) {
    int i = blockIdx.x * blockDim.x + threadIdx.x;
    if (i < n) {
        int p = atomicAdd(&cursor[i], 1);
        col16[offs[i] + p] = (ushort)i;
    }
}

// ---------------- weight transpose+cast: W[K][128] f32 -> WT[128][K] bf16 ----------------

__global__ void k_tcast(const float* __restrict__ W, ushort* __restrict__ WT, int K) {
    int idx = blockIdx.x * 256 + threadIdx.x;
    if (idx < K * 128) {
        int k = idx >> 7, c = idx & 127;
        WT[(size_t)c * K + k] = f2b(W[idx]);
    }
}

// ---------------- bf16 MFMA GEMM -> SLICED output ----------------
// Hs layout: [slice(8)][node(M)][16 feats], element = bf16.
// Hs[((slice*M)+row)*16 + feat] = (A@W)[row][slice*16+feat] * rowscale[row]

template<int A_F32>
__global__ __launch_bounds__(256) void k_gemm(const void* __restrict__ Aptr,
                                              const ushort* __restrict__ WT,
                                              const float* __restrict__ rowscale,
                                              ushort* __restrict__ Hs, int M, int K) {
    __shared__ ushort As[128][40];  // pad 40: <=2-way bank conflict (free)
    __shared__ ushort Bs[128][40];

    const int tid = threadIdx.x;
    const int wid = tid >> 6, lane = tid & 63;
    const int wr = wid >> 1, wc = wid & 1;
    const int lr = lane & 15, lk = (lane >> 4) * 8;
    const int rowbase = blockIdx.x * 128;

    f32x4 acc[4][4];
#pragma unroll
    for (int i = 0; i < 4; i++)
#pragma unroll
        for (int j = 0; j < 4; j++) acc[i][j] = (f32x4)0.f;

    const int sr = tid >> 1;
    const int sh = (tid & 1) * 16;

    for (int k0 = 0; k0 < K; k0 += 32) {
        {
            int gr = rowbase + sr;
            ushort tmp[16];
            if (A_F32) {
                const float* A = (const float*)Aptr;
                if (gr < M) {
                    const float* p = A + (size_t)gr * K + k0 + sh;
#pragma unroll
                    for (int q = 0; q < 4; q++) {
                        float4 v = *(const float4*)(p + q * 4);
                        tmp[q * 4 + 0] = f2b(v.x); tmp[q * 4 + 1] = f2b(v.y);
                        tmp[q * 4 + 2] = f2b(v.z); tmp[q * 4 + 3] = f2b(v.w);
                    }
                } else {
#pragma unroll
                    for (int q = 0; q < 16; q++) tmp[q] = 0;
                }
            } else {
                const ushort* A = (const ushort*)Aptr;
                if (gr < M) {
                    const ushort* p = A + (size_t)gr * K + k0 + sh;
                    *(short8*)&tmp[0] = *(const short8*)(p);
                    *(short8*)&tmp[8] = *(const short8*)(p + 8);
                } else {
#pragma unroll
                    for (int q = 0; q < 16; q++) tmp[q] = 0;
                }
            }
            *(short8*)&As[sr][sh]     = *(short8*)&tmp[0];
            *(short8*)&As[sr][sh + 8] = *(short8*)&tmp[8];
        }
        {
#pragma unroll
            for (int t = 0; t < 2; t++) {
                int c = tid + t * 256;
                int row = c >> 2, q = c & 3;
                short8 v = *(const short8*)(WT + (size_t)row * K + k0 + q * 8);
                *(short8*)&Bs[row][q * 8] = v;
            }
        }
        __syncthreads();

        short8 af[4], bfv[4];
#pragma unroll
        for (int i = 0; i < 4; i++) af[i] = *(const short8*)&As[wr * 64 + i * 16 + lr][lk];
#pragma unroll
        for (int j = 0; j < 4; j++) bfv[j] = *(const short8*)&Bs[wc * 64 + j * 16 + lr][lk];
#pragma unroll
        for (int i = 0; i < 4; i++)
#pragma unroll
            for (int j = 0; j < 4; j++)
                acc[i][j] = __builtin_amdgcn_mfma_f32_16x16x32_bf16(af[i], bfv[j], acc[i][j], 0, 0, 0);
        __syncthreads();
    }

#pragma unroll
    for (int i = 0; i < 4; i++) {
#pragma unroll
        for (int r = 0; r < 4; r++) {
            int row = rowbase + wr * 64 + i * 16 + (lane >> 4) * 4 + r;
            if (row < M) {
                float sc = rowscale[row];
#pragma unroll
                for (int j = 0; j < 4; j++) {
                    int slice = wc * 4 + j;     // colg>>4
                    Hs[((size_t)slice * M + row) * 16 + lr] = f2b(acc[i][j][r] * sc);
                }
            }
        }
    }
}

// ---------------- sliced aggregation ----------------
// Block b handles slice s = b&7 (lands on one XCD via round-robin dispatch).
// Wave per node iteration; lanes: e8 = lane>>3 (edge sub-batch), q = lane&7 (feat pair).
// out[v][s*16 + 2q .. +1] = relu( dinv[v] * sum_{src} hs[s][src][2q..] + bias )  (bf16 row-major)

static __device__ __forceinline__ void gs4(const ushort* __restrict__ hsl, int myc,
                                           int j, int cnt, int e8, int q,
                                           float& a0, float& a1) {
    uint pk[4];
#pragma unroll
    for (int b = 0; b < 4; b++) {
        int idx = j + b * 8 + e8;
        int sc = __shfl(myc, idx & 63);
        uint v = *(const uint*)((const char*)hsl + (size_t)sc * 32 + q * 4);
        pk[b] = (idx < cnt) ? v : 0u;
    }
#pragma unroll
    for (int b = 0; b < 4; b++) {
        a0 += b2f(pk[b] & 0xffffu);
        a1 += b2f(pk[b] >> 16);
    }
}

__global__ __launch_bounds__(256) void k_aggs(const ushort* __restrict__ hs,
                                              const int* __restrict__ offs,
                                              const ushort* __restrict__ col16,
                                              const float* __restrict__ dinv,
                                              const float* __restrict__ bias,
                                              ushort* __restrict__ outp, int n) {
    const int b = blockIdx.x;
    const int s = b & 7;
    const int wid = threadIdx.x >> 6, lane = threadIdx.x & 63;
    const int e8 = lane >> 3, q = lane & 7;
    const int group = (b >> 3) * 4 + wid;
    const int ngroups = (gridDim.x >> 3) * 4;
    const ushort* hsl = hs + (size_t)s * n * 16;

    const float b0 = bias[s * 16 + q * 2 + 0];
    const float b1 = bias[s * 16 + q * 2 + 1];

    for (int v = group; v < n; v += ngroups) {
        int e0 = offs[v], e1 = offs[v + 1];
        float a0 = 0.f, a1 = 0.f;
        for (int base = e0; base < e1; base += 64) {
            int cnt = e1 - base; if (cnt > 64) cnt = 64;
            int myc = (base + lane < e1) ? (int)col16[base + lane] : 0;
            for (int j = 0; j < cnt; j += 32)
                gs4(hsl, myc, j, cnt, e8, q, a0, a1);
        }
        // reduce across the 8 e8-groups (q preserved under xor of bits >=3)
        a0 += __shfl_xor(a0, 8);  a1 += __shfl_xor(a1, 8);
        a0 += __shfl_xor(a0, 16); a1 += __shfl_xor(a1, 16);
        a0 += __shfl_xor(a0, 32); a1 += __shfl_xor(a1, 32);

        float dvv = dinv[v];
        float r0 = fmaxf(fmaf(a0, dvv, b0), 0.f);
        float r1 = fmaxf(fmaf(a1, dvv, b1), 0.f);
        if (lane < 8) {
            uint pk = (uint)f2b(r0) | ((uint)f2b(r1) << 16);
            *(uint*)(outp + (size_t)v * 128 + s * 16 + q * 2) = pk;
        }
    }
}

// ---------------- classifier + log_softmax (bf16 hidden input, row-major) ----------------
// block 256 = 4 waves, wave per node; j = class, c = 32-feat chunk

__global__ __launch_bounds__(256) void k_classify(const ushort* __restrict__ h,
                                                  const float* __restrict__ Wc,
                                                  const float* __restrict__ bc,
                                                  float* __restrict__ out, int n) {
    __shared__ float Ws[128 * 16];
    int tid = threadIdx.x;
#pragma unroll
    for (int t = 0; t < 8; t++) Ws[tid + 256 * t] = Wc[tid + 256 * t];
    __syncthreads();

    int wid = tid >> 6, lane = tid & 63;
    int v = blockIdx.x * 4 + wid;
    if (v >= n) return;

    int j = lane & 15, c = lane >> 4;
    const ushort* hv = h + (size_t)v * 128 + c * 32;
    float acc = 0.f;
#pragma unroll
    for (int t = 0; t < 16; t++) {
        uint pk = *(const uint*)(hv + t * 2);
        acc = fmaf(b2f(pk & 0xffffu), Ws[(c * 32 + t * 2 + 0) * 16 + j], acc);
        acc = fmaf(b2f(pk >> 16),     Ws[(c * 32 + t * 2 + 1) * 16 + j], acc);
    }
    acc += __shfl_xor(acc, 16);
    acc += __shfl_xor(acc, 32);
    acc += bc[j];

    float m = acc;
#pragma unroll
    for (int o = 8; o >= 1; o >>= 1) m = fmaxf(m, __shfl_xor(m, o));
    float s = expf(acc - m);
#pragma unroll
    for (int o = 8; o >= 1; o >>= 1) s += __shfl_xor(s, o);
    if (lane < 16) out[(size_t)v * 16 + j] = acc - m - logf(s);
}

// ---------------- launch ----------------

extern "C" void kernel_launch(void* const* d_in, const int* in_sizes, int n_in,
                              void* d_out, int out_size, void* d_ws, size_t ws_size,
                              hipStream_t stream) {
    const float* x  = (const float*)d_in[0];
    const int* eidx = (const int*)d_in[1];
    const float* W1 = (const float*)d_in[2];
    const float* b1 = (const float*)d_in[3];
    const float* W2 = (const float*)d_in[4];
    const float* b2 = (const float*)d_in[5];
    const float* Wc = (const float*)d_in[6];
    const float* bc = (const float*)d_in[7];
    float* out = (float*)d_out;

    const int N = in_sizes[0] / NFEAT;   // 50000  (< 65536 -> ushort node ids)
    const int E = in_sizes[1] / 2;       // 800000
    const int* src = eidx;
    const int* dst = eidx + E;

    char* p = (char*)d_ws;
    auto alloc = [&](size_t bytes) { char* r = p; p += (bytes + 255) & ~(size_t)255; return r; };
    int*    deg    = (int*)   alloc((size_t)N * 4);
    float*  dinv   = (float*) alloc((size_t)N * 4);
    int*    offs   = (int*)   alloc((size_t)(N + 1) * 4);
    int*    cursor = (int*)   alloc((size_t)N * 4);
    ushort* col16  = (ushort*)alloc((size_t)(E + N) * 2);
    int*    bsum   = (int*)   alloc((size_t)256 * 4);
    ushort* W1T    = (ushort*)alloc((size_t)128 * NFEAT * 2);
    ushort* W2T    = (ushort*)alloc((size_t)128 * NHID * 2);
    ushort* hs     = (ushort*)alloc((size_t)N * NHID * 2);   // sliced GEMM out (reused both layers)
    ushort* g1     = (ushort*)alloc((size_t)N * NHID * 2);   // agg1 out, row-major bf16
    ushort* g2     = (ushort*)alloc((size_t)N * NHID * 2);   // agg2 out, row-major bf16

    const int nb = (N + SCAN_BS - 1) / SCAN_BS;

    k_init_deg<<<(N + 255) / 256, 256, 0, stream>>>(deg, N);
    k_count<<<(E + 255) / 256, 256, 0, stream>>>(dst, E, deg);
    k_dinv<<<(N + 255) / 256, 256, 0, stream>>>(deg, dinv, cursor, N);
    k_scan1<<<nb, SCAN_BS, 0, stream>>>(deg, offs, bsum, N);
    k_scan2<<<1, 64, 0, stream>>>(bsum, offs, nb, N);
    k_scan3<<<nb, SCAN_BS, 0, stream>>>(offs, bsum, N);
    k_fill_edges<<<(E + 255) / 256, 256, 0, stream>>>(src, dst, E, offs, cursor, col16);
    k_fill_self<<<(N + 255) / 256, 256, 0, stream>>>(offs, cursor, col16, N);

    k_tcast<<<(NFEAT * 128 + 255) / 256, 256, 0, stream>>>(W1, W1T, NFEAT);
    k_tcast<<<(NHID * 128 + 255) / 256, 256, 0, stream>>>(W2, W2T, NHID);

    const int gblocks = (N + 127) / 128;
    // layer 1
    k_gemm<1><<<gblocks, 256, 0, stream>>>(x, W1T, dinv, hs, N, NFEAT);
    k_aggs<<<AGG_BLOCKS, 256, 0, stream>>>(hs, offs, col16, dinv, b1, g1, N);
    // layer 2
    k_gemm<0><<<gblocks, 256, 0, stream>>>(g1, W2T, dinv, hs, N, NHID);
    k_aggs<<<AGG_BLOCKS, 256, 0, stream>>>(hs, offs, col16, dinv, b2, g2, N);
    // classifier
    k_classify<<<(N + 3) / 4, 256, 0, stream>>>(g2, Wc, bc, out, N);
}

// Round 6
// 292.780 us; speedup vs baseline: 1.1082x; 1.1082x over previous
//
#include <hip/hip_runtime.h>
#include <math.h>

#define NFEAT 512
#define NHID  128
#define NCLASS 16
#define SCAN_BS 512
#define AGG_BLOCKS 2048   // multiple of 8; slice = (blockIdx&7)>>1

typedef __attribute__((ext_vector_type(8))) short short8;
typedef __attribute__((ext_vector_type(4))) float f32x4;

static __device__ __forceinline__ ushort f2b(float f) {
    union { float f; uint u; } v; v.f = f;
    uint r = v.u + 0x7FFFu + ((v.u >> 16) & 1u);   // round-to-nearest-even
    return (ushort)(r >> 16);
}
static __device__ __forceinline__ float b2f_lo(uint bits) {
    union { uint u; float f; } v; v.u = bits << 16; return v.f;
}
static __device__ __forceinline__ float b2f_hi(uint bits) {
    union { uint u; float f; } v; v.u = bits & 0xffff0000u; return v.f;
}
static __device__ __forceinline__ float b2f(uint bits) {
    union { uint u; float f; } v; v.u = bits << 16; return v.f;
}

// ---------------- CSR build (group-padded, groups of 8 slots) ----------------

__global__ void k_init_deg(int* __restrict__ deg, int n) {
    int i = blockIdx.x * blockDim.x + threadIdx.x;
    if (i < n) deg[i] = 1;  // self-loop
}

__global__ void k_count(const int* __restrict__ dst, int e, int* __restrict__ deg) {
    int i = blockIdx.x * blockDim.x + threadIdx.x;
    if (i < e) atomicAdd(&deg[dst[i]], 1);
}

// dinv + per-node group count + cursor reset
__global__ void k_dinv(const int* __restrict__ deg, float* __restrict__ dinv,
                       int* __restrict__ gcnt, int* __restrict__ cursor, int n) {
    int i = blockIdx.x * blockDim.x + threadIdx.x;
    if (i < n) {
        dinv[i] = rsqrtf((float)deg[i]);
        gcnt[i] = (deg[i] + 7) >> 3;
        cursor[i] = 0;
    }
}

__global__ void k_scan1(const int* __restrict__ in, int* __restrict__ offs,
                        int* __restrict__ bsum, int n) {
    __shared__ int s[SCAN_BS];
    int t = threadIdx.x;
    int i = blockIdx.x * SCAN_BS + t;
    int v = (i < n) ? in[i] : 0;
    s[t] = v;
    for (int off = 1; off < SCAN_BS; off <<= 1) {
        __syncthreads();
        int x = (t >= off) ? s[t - off] : 0;
        __syncthreads();
        s[t] += x;
    }
    __syncthreads();
    if (i < n) offs[i] = s[t] - v;
    if (t == SCAN_BS - 1) bsum[blockIdx.x] = s[t];
}

__global__ void k_scan2(int* __restrict__ bsum, int* __restrict__ offs, int nb, int n) {
    if (threadIdx.x == 0 && blockIdx.x == 0) {
        int run = 0;
        for (int b = 0; b < nb; b++) { int x = bsum[b]; bsum[b] = run; run += x; }
        offs[n] = run;   // = total groups G
    }
}

__global__ void k_scan3(int* __restrict__ offs, const int* __restrict__ bsum, int n) {
    int i = blockIdx.x * SCAN_BS + threadIdx.x;
    if (i < n) offs[i] += bsum[blockIdx.x];
}

__global__ void k_fill_edges(const int* __restrict__ src, const int* __restrict__ dst, int e,
                             const int* __restrict__ goffs, int* __restrict__ cursor,
                             ushort* __restrict__ colp) {
    int i = blockIdx.x * blockDim.x + threadIdx.x;
    if (i < e) {
        int d = dst[i];
        int p = atomicAdd(&cursor[d], 1);
        colp[(size_t)goffs[d] * 8 + p] = (ushort)src[i];
    }
}

__global__ void k_fill_self(const int* __restrict__ goffs, int* __restrict__ cursor,
                            ushort* __restrict__ colp, int n) {
    int i = blockIdx.x * blockDim.x + threadIdx.x;
    if (i < n) {
        int p = atomicAdd(&cursor[i], 1);
        colp[(size_t)goffs[i] * 8 + p] = (ushort)i;
    }
}

// pad tail slots with sentinel node n (zero row); fill gnode; write end sentinels
__global__ void k_fill_pad(const int* __restrict__ goffs, const int* __restrict__ deg,
                           ushort* __restrict__ colp, int* __restrict__ gnode, int n) {
    int i = blockIdx.x * blockDim.x + threadIdx.x;
    if (i < n) {
        int g0 = goffs[i], g1 = goffs[i + 1];
        size_t base = (size_t)g0 * 8;
        int slots = (g1 - g0) * 8;
        for (int p = deg[i]; p < slots; p++) colp[base + p] = (ushort)n;
        for (int g = g0; g < g1; g++) gnode[g] = i;
        if (i == 0) {
            int G = goffs[n];
            gnode[G] = -1;  // boundary sentinel
            for (int k = 0; k < 8; k++) colp[(size_t)G * 8 + k] = (ushort)n;
        }
    }
}

// zero the sentinel row (row n) of each of the 4 slices
__global__ void k_zero_sent(ushort* __restrict__ hs, int n) {
    int t = threadIdx.x;
    if (t < 128) {
        int s = t >> 5, f = t & 31;
        hs[((size_t)s * (n + 1) + n) * 32 + f] = 0;
    }
}

// ---------------- weight transpose+cast: W[K][128] f32 -> WT[128][K] bf16 ----------------

__global__ void k_tcast(const float* __restrict__ W, ushort* __restrict__ WT, int K) {
    int idx = blockIdx.x * 256 + threadIdx.x;
    if (idx < K * 128) {
        int k = idx >> 7, c = idx & 127;
        WT[(size_t)c * K + k] = f2b(W[idx]);
    }
}

// ---------------- bf16 MFMA GEMM -> 4-slice output ----------------
// Hs layout: [slice(4)][node(M+1)][32 feats] bf16, pre-scaled by rowscale[row].

template<int A_F32>
__global__ __launch_bounds__(256) void k_gemm(const void* __restrict__ Aptr,
                                              const ushort* __restrict__ WT,
                                              const float* __restrict__ rowscale,
                                              ushort* __restrict__ Hs, int M, int K) {
    __shared__ ushort As[128][40];  // pad 40: <=2-way bank conflict (free)
    __shared__ ushort Bs[128][40];

    const int tid = threadIdx.x;
    const int wid = tid >> 6, lane = tid & 63;
    const int wr = wid >> 1, wc = wid & 1;
    const int lr = lane & 15, lk = (lane >> 4) * 8;
    const int rowbase = blockIdx.x * 128;

    f32x4 acc[4][4];
#pragma unroll
    for (int i = 0; i < 4; i++)
#pragma unroll
        for (int j = 0; j < 4; j++) acc[i][j] = (f32x4)0.f;

    const int sr = tid >> 1;
    const int sh = (tid & 1) * 16;

    for (int k0 = 0; k0 < K; k0 += 32) {
        {
            int gr = rowbase + sr;
            ushort tmp[16];
            if (A_F32) {
                const float* A = (const float*)Aptr;
                if (gr < M) {
                    const float* p = A + (size_t)gr * K + k0 + sh;
#pragma unroll
                    for (int q = 0; q < 4; q++) {
                        float4 v = *(const float4*)(p + q * 4);
                        tmp[q * 4 + 0] = f2b(v.x); tmp[q * 4 + 1] = f2b(v.y);
                        tmp[q * 4 + 2] = f2b(v.z); tmp[q * 4 + 3] = f2b(v.w);
                    }
                } else {
#pragma unroll
                    for (int q = 0; q < 16; q++) tmp[q] = 0;
                }
            } else {
                const ushort* A = (const ushort*)Aptr;
                if (gr < M) {
                    const ushort* p = A + (size_t)gr * K + k0 + sh;
                    *(short8*)&tmp[0] = *(const short8*)(p);
                    *(short8*)&tmp[8] = *(const short8*)(p + 8);
                } else {
#pragma unroll
                    for (int q = 0; q < 16; q++) tmp[q] = 0;
                }
            }
            *(short8*)&As[sr][sh]     = *(short8*)&tmp[0];
            *(short8*)&As[sr][sh + 8] = *(short8*)&tmp[8];
        }
        {
#pragma unroll
            for (int t = 0; t < 2; t++) {
                int c = tid + t * 256;
                int row = c >> 2, q = c & 3;
                short8 v = *(const short8*)(WT + (size_t)row * K + k0 + q * 8);
                *(short8*)&Bs[row][q * 8] = v;
            }
        }
        __syncthreads();

        short8 af[4], bfv[4];
#pragma unroll
        for (int i = 0; i < 4; i++) af[i] = *(const short8*)&As[wr * 64 + i * 16 + lr][lk];
#pragma unroll
        for (int j = 0; j < 4; j++) bfv[j] = *(const short8*)&Bs[wc * 64 + j * 16 + lr][lk];
#pragma unroll
        for (int i = 0; i < 4; i++)
#pragma unroll
            for (int j = 0; j < 4; j++)
                acc[i][j] = __builtin_amdgcn_mfma_f32_16x16x32_bf16(af[i], bfv[j], acc[i][j], 0, 0, 0);
        __syncthreads();
    }

#pragma unroll
    for (int i = 0; i < 4; i++) {
#pragma unroll
        for (int r = 0; r < 4; r++) {
            int row = rowbase + wr * 64 + i * 16 + (lane >> 4) * 4 + r;
            if (row < M) {
                float sc = rowscale[row];
#pragma unroll
                for (int j = 0; j < 4; j++) {
                    int slice = wc * 2 + (j >> 1);
                    int f = (j & 1) * 16 + lr;
                    Hs[((size_t)slice * (M + 1) + row) * 32 + f] = f2b(acc[i][j][r] * sc);
                }
            }
        }
    }
}

// ---------------- edge-major segmented aggregation over 4 slices ----------------
// Wave owns a run of 8-edge groups; lanes: e8 = lane>>3 (edge in group), q = lane&7
// (8B = 4 feats). Flush at node boundaries (wave-uniform). out row-major bf16 [n][128].

__global__ __launch_bounds__(256) void k_aggs(const ushort* __restrict__ hs,
                                              const int* __restrict__ goffs,
                                              const ushort* __restrict__ colp,
                                              const int* __restrict__ gnode,
                                              const float* __restrict__ dinv,
                                              const float* __restrict__ bias,
                                              ushort* __restrict__ outp, int n) {
    const int b = blockIdx.x;
    const int s = (b & 7) >> 1;                 // slice 0..3, pinned to XCD pair
    const int wid = threadIdx.x >> 6, lane = threadIdx.x & 63;
    const int e8 = lane >> 3, q = lane & 7;

    const int G = goffs[n];
    const int nranks = gridDim.x;               // (grid/8)*2*4 == grid
    const int rank = ((b >> 3) * 2 + (b & 1)) * 4 + wid;
    const int run = (G + nranks - 1) / nranks;
    int gs = rank * run;
    if (gs >= G) return;
    int ge = gs + run; if (ge > G) ge = G;
    if (gs > 0) {
        int pv = gnode[gs - 1];
        while (gs < ge && gnode[gs] == pv) gs++;   // skip previous wave's boundary node
        if (gs >= ge) return;
    }

    const ushort* hsl = hs + (size_t)s * (n + 1) * 32;
    const float4 bv = *(const float4*)(bias + s * 32 + q * 4);

    int g = gs;
    int v = gnode[g];
    uint sc = colp[(size_t)g * 8 + e8];
    float dv = dinv[v];
    float a0 = 0.f, a1 = 0.f, a2 = 0.f, a3 = 0.f;

    while (true) {
        // prefetch next step
        int v_n = gnode[g + 1];
        uint sc_n = colp[(size_t)(g + 1) * 8 + e8];
        float dv_n = dinv[v_n < 0 ? 0 : v_n];
        // gather current group's 8 rows x 8B
        uint2 pk = *(const uint2*)(hsl + (size_t)sc * 32 + q * 4);
        a0 += b2f_lo(pk.x); a1 += b2f_hi(pk.x);
        a2 += b2f_lo(pk.y); a3 += b2f_hi(pk.y);

        if (v_n != v) {   // wave-uniform node boundary -> flush
            float r0 = a0, r1 = a1, r2 = a2, r3 = a3;
#pragma unroll
            for (int off = 8; off <= 32; off <<= 1) {
                r0 += __shfl_xor(r0, off); r1 += __shfl_xor(r1, off);
                r2 += __shfl_xor(r2, off); r3 += __shfl_xor(r3, off);
            }
            r0 = fmaxf(fmaf(r0, dv, bv.x), 0.f);
            r1 = fmaxf(fmaf(r1, dv, bv.y), 0.f);
            r2 = fmaxf(fmaf(r2, dv, bv.z), 0.f);
            r3 = fmaxf(fmaf(r3, dv, bv.w), 0.f);
            if (lane < 8) {
                uint2 u;
                u.x = (uint)f2b(r0) | ((uint)f2b(r1) << 16);
                u.y = (uint)f2b(r2) | ((uint)f2b(r3) << 16);
                *(uint2*)(outp + (size_t)v * 128 + s * 32 + q * 4) = u;
            }
            if (g + 1 >= ge) break;
            v = v_n; dv = dv_n;
            a0 = a1 = a2 = a3 = 0.f;
        } else {
            dv = dv_n;
        }
        g++; sc = sc_n;
    }
}

// ---------------- classifier + log_softmax (bf16 hidden input, row-major) ----------------

__global__ __launch_bounds__(256) void k_classify(const ushort* __restrict__ h,
                                                  const float* __restrict__ Wc,
                                                  const float* __restrict__ bc,
                                                  float* __restrict__ out, int n) {
    __shared__ float Ws[128 * 16];
    int tid = threadIdx.x;
#pragma unroll
    for (int t = 0; t < 8; t++) Ws[tid + 256 * t] = Wc[tid + 256 * t];
    __syncthreads();

    int wid = tid >> 6, lane = tid & 63;
    int v = blockIdx.x * 4 + wid;
    if (v >= n) return;

    int j = lane & 15, c = lane >> 4;
    const ushort* hv = h + (size_t)v * 128 + c * 32;
    float acc = 0.f;
#pragma unroll
    for (int t = 0; t < 16; t++) {
        uint pk = *(const uint*)(hv + t * 2);
        acc = fmaf(b2f_lo(pk), Ws[(c * 32 + t * 2 + 0) * 16 + j], acc);
        acc = fmaf(b2f_hi(pk), Ws[(c * 32 + t * 2 + 1) * 16 + j], acc);
    }
    acc += __shfl_xor(acc, 16);
    acc += __shfl_xor(acc, 32);
    acc += bc[j];

    float m = acc;
#pragma unroll
    for (int o = 8; o >= 1; o >>= 1) m = fmaxf(m, __shfl_xor(m, o));
    float sum = expf(acc - m);
#pragma unroll
    for (int o = 8; o >= 1; o >>= 1) sum += __shfl_xor(sum, o);
    if (lane < 16) out[(size_t)v * 16 + j] = acc - m - logf(sum);
}

// ---------------- launch ----------------

extern "C" void kernel_launch(void* const* d_in, const int* in_sizes, int n_in,
                              void* d_out, int out_size, void* d_ws, size_t ws_size,
                              hipStream_t stream) {
    const float* x  = (const float*)d_in[0];
    const int* eidx = (const int*)d_in[1];
    const float* W1 = (const float*)d_in[2];
    const float* b1 = (const float*)d_in[3];
    const float* W2 = (const float*)d_in[4];
    const float* b2 = (const float*)d_in[5];
    const float* Wc = (const float*)d_in[6];
    const float* bc = (const float*)d_in[7];
    float* out = (float*)d_out;

    const int N = in_sizes[0] / NFEAT;   // 50000 (< 65536 -> ushort node ids)
    const int E = in_sizes[1] / 2;       // 800000
    const int* src = eidx;
    const int* dst = eidx + E;

    char* p = (char*)d_ws;
    auto alloc = [&](size_t bytes) { char* r = p; p += (bytes + 255) & ~(size_t)255; return r; };
    int*    deg    = (int*)   alloc((size_t)N * 4);
    float*  dinv   = (float*) alloc((size_t)N * 4);
    int*    gcnt   = (int*)   alloc((size_t)N * 4);
    int*    goffs  = (int*)   alloc((size_t)(N + 1) * 4);
    int*    cursor = (int*)   alloc((size_t)N * 4);
    ushort* colp   = (ushort*)alloc(((size_t)E + 8ull * N + 16) * 2); // padded slots + sentinel grp
    int*    gnode  = (int*)   alloc(((size_t)E / 8 + N + 2) * 4);
    int*    bsum   = (int*)   alloc((size_t)256 * 4);
    ushort* W1T    = (ushort*)alloc((size_t)128 * NFEAT * 2);
    ushort* W2T    = (ushort*)alloc((size_t)128 * NHID * 2);
    ushort* hs     = (ushort*)alloc((size_t)(N + 1) * NHID * 2);  // 4 slices x (N+1) x 32
    ushort* g1     = (ushort*)alloc((size_t)N * NHID * 2);        // agg1 out, row-major bf16
    ushort* g2     = (ushort*)alloc((size_t)N * NHID * 2);        // agg2 out, row-major bf16

    const int nb = (N + SCAN_BS - 1) / SCAN_BS;

    k_init_deg<<<(N + 255) / 256, 256, 0, stream>>>(deg, N);
    k_count<<<(E + 255) / 256, 256, 0, stream>>>(dst, E, deg);
    k_dinv<<<(N + 255) / 256, 256, 0, stream>>>(deg, dinv, gcnt, cursor, N);
    k_scan1<<<nb, SCAN_BS, 0, stream>>>(gcnt, goffs, bsum, N);
    k_scan2<<<1, 64, 0, stream>>>(bsum, goffs, nb, N);
    k_scan3<<<nb, SCAN_BS, 0, stream>>>(goffs, bsum, N);
    k_fill_edges<<<(E + 255) / 256, 256, 0, stream>>>(src, dst, E, goffs, cursor, colp);
    k_fill_self<<<(N + 255) / 256, 256, 0, stream>>>(goffs, cursor, colp, N);
    k_fill_pad<<<(N + 255) / 256, 256, 0, stream>>>(goffs, deg, colp, gnode, N);

    k_tcast<<<(NFEAT * 128 + 255) / 256, 256, 0, stream>>>(W1, W1T, NFEAT);
    k_tcast<<<(NHID * 128 + 255) / 256, 256, 0, stream>>>(W2, W2T, NHID);
    k_zero_sent<<<1, 128, 0, stream>>>(hs, N);

    const int gblocks = (N + 127) / 128;
    // layer 1
    k_gemm<1><<<gblocks, 256, 0, stream>>>(x, W1T, dinv, hs, N, NFEAT);
    k_aggs<<<AGG_BLOCKS, 256, 0, stream>>>(hs, goffs, colp, gnode, dinv, b1, g1, N);
    // layer 2
    k_gemm<0><<<gblocks, 256, 0, stream>>>(g1, W2T, dinv, hs, N, NHID);
    k_aggs<<<AGG_BLOCKS, 256, 0, stream>>>(hs, goffs, colp, gnode, dinv, b2, g2, N);
    // classifier
    k_classify<<<(N + 3) / 4, 256, 0, stream>>>(g2, Wc, bc, out, N);
}

// Round 7
// 275.977 us; speedup vs baseline: 1.1757x; 1.0609x over previous
//
#include <hip/hip_runtime.h>
#include <math.h>

#define NFEAT 512
#define NHID  128
#define NCLASS 16
#define SCAN_BS 512
#define AGG_BLOCKS 2048   // multiple of 8; slice = (blockIdx&7)>>1

typedef __attribute__((ext_vector_type(8))) short short8;
typedef __attribute__((ext_vector_type(4))) float f32x4;

static __device__ __forceinline__ ushort f2b(float f) {
    union { float f; uint u; } v; v.f = f;
    uint r = v.u + 0x7FFFu + ((v.u >> 16) & 1u);   // round-to-nearest-even
    return (ushort)(r >> 16);
}
static __device__ __forceinline__ float b2f_lo(uint bits) {
    union { uint u; float f; } v; v.u = bits << 16; return v.f;
}
static __device__ __forceinline__ float b2f_hi(uint bits) {
    union { uint u; float f; } v; v.u = bits & 0xffff0000u; return v.f;
}
static __device__ __forceinline__ float b2f(uint bits) {
    union { uint u; float f; } v; v.u = bits << 16; return v.f;
}

// ---------------- CSR build (group-padded, groups of 8 slots) ----------------

__global__ void k_init_deg(int* __restrict__ deg, int n) {
    int i = blockIdx.x * blockDim.x + threadIdx.x;
    if (i < n) deg[i] = 1;  // self-loop
}

__global__ void k_count(const int* __restrict__ dst, int e, int* __restrict__ deg) {
    int i = blockIdx.x * blockDim.x + threadIdx.x;
    if (i < e) atomicAdd(&deg[dst[i]], 1);
}

// dinv + per-node group count + cursor reset
__global__ void k_dinv(const int* __restrict__ deg, float* __restrict__ dinv,
                       int* __restrict__ gcnt, int* __restrict__ cursor, int n) {
    int i = blockIdx.x * blockDim.x + threadIdx.x;
    if (i < n) {
        dinv[i] = rsqrtf((float)deg[i]);
        gcnt[i] = (deg[i] + 7) >> 3;
        cursor[i] = 0;
    }
}

__global__ void k_scan1(const int* __restrict__ in, int* __restrict__ offs,
                        int* __restrict__ bsum, int n) {
    __shared__ int s[SCAN_BS];
    int t = threadIdx.x;
    int i = blockIdx.x * SCAN_BS + t;
    int v = (i < n) ? in[i] : 0;
    s[t] = v;
    for (int off = 1; off < SCAN_BS; off <<= 1) {
        __syncthreads();
        int x = (t >= off) ? s[t - off] : 0;
        __syncthreads();
        s[t] += x;
    }
    __syncthreads();
    if (i < n) offs[i] = s[t] - v;
    if (t == SCAN_BS - 1) bsum[blockIdx.x] = s[t];
}

__global__ void k_scan2(int* __restrict__ bsum, int* __restrict__ offs, int nb, int n) {
    if (threadIdx.x == 0 && blockIdx.x == 0) {
        int run = 0;
        for (int b = 0; b < nb; b++) { int x = bsum[b]; bsum[b] = run; run += x; }
        offs[n] = run;   // = total groups G
    }
}

__global__ void k_scan3(int* __restrict__ offs, const int* __restrict__ bsum, int n) {
    int i = blockIdx.x * SCAN_BS + threadIdx.x;
    if (i < n) offs[i] += bsum[blockIdx.x];
}

__global__ void k_fill_edges(const int* __restrict__ src, const int* __restrict__ dst, int e,
                             const int* __restrict__ goffs, int* __restrict__ cursor,
                             ushort* __restrict__ colp) {
    int i = blockIdx.x * blockDim.x + threadIdx.x;
    if (i < e) {
        int d = dst[i];
        int p = atomicAdd(&cursor[d], 1);
        colp[(size_t)goffs[d] * 8 + p] = (ushort)src[i];
    }
}

// self-loop slot (= deg-1, since cursor ended at deg-1) + pad tail + gnode + sentinels
// + zero the sentinel rows of hs
__global__ void k_fill_tail(const int* __restrict__ goffs, const int* __restrict__ deg,
                            ushort* __restrict__ colp, int* __restrict__ gnode,
                            ushort* __restrict__ hs, int n) {
    int i = blockIdx.x * blockDim.x + threadIdx.x;
    if (i < 128) {  // zero sentinel row (node n) of each of the 4 slices
        int s = i >> 5, f = i & 31;
        hs[((size_t)s * (n + 1) + n) * 32 + f] = 0;
    }
    if (i < n) {
        int g0 = goffs[i], g1 = goffs[i + 1];
        size_t base = (size_t)g0 * 8;
        int d = deg[i];
        int slots = (g1 - g0) * 8;
        colp[base + d - 1] = (ushort)i;                 // self-loop
        for (int p = d; p < slots; p++) colp[base + p] = (ushort)n;  // pad -> zero row
        for (int g = g0; g < g1; g++) gnode[g] = i;
        if (i == 0) {
            int G = goffs[n];
            gnode[G] = -1;  // boundary sentinel
            for (int k = 0; k < 16; k++) colp[(size_t)G * 8 + k] = (ushort)n;  // 2 sentinel groups
        }
    }
}

// ---------------- weight transpose+cast: W[K][128] f32 -> WT[128][K] bf16 ----------------

__global__ void k_tcast(const float* __restrict__ W, ushort* __restrict__ WT, int K) {
    int idx = blockIdx.x * 256 + threadIdx.x;
    if (idx < K * 128) {
        int k = idx >> 7, c = idx & 127;
        WT[(size_t)c * K + k] = f2b(W[idx]);
    }
}

// ---------------- bf16 MFMA GEMM -> 4-slice output ----------------
// Hs layout: [slice(4)][node(M+1)][32 feats] bf16, pre-scaled by rowscale[row].

template<int A_F32>
__global__ __launch_bounds__(256) void k_gemm(const void* __restrict__ Aptr,
                                              const ushort* __restrict__ WT,
                                              const float* __restrict__ rowscale,
                                              ushort* __restrict__ Hs, int M, int K) {
    __shared__ ushort As[128][40];  // pad 40: <=2-way bank conflict (free)
    __shared__ ushort Bs[128][40];

    const int tid = threadIdx.x;
    const int wid = tid >> 6, lane = tid & 63;
    const int wr = wid >> 1, wc = wid & 1;
    const int lr = lane & 15, lk = (lane >> 4) * 8;
    const int rowbase = blockIdx.x * 128;

    f32x4 acc[4][4];
#pragma unroll
    for (int i = 0; i < 4; i++)
#pragma unroll
        for (int j = 0; j < 4; j++) acc[i][j] = (f32x4)0.f;

    const int sr = tid >> 1;
    const int sh = (tid & 1) * 16;

    for (int k0 = 0; k0 < K; k0 += 32) {
        {
            int gr = rowbase + sr;
            ushort tmp[16];
            if (A_F32) {
                const float* A = (const float*)Aptr;
                if (gr < M) {
                    const float* p = A + (size_t)gr * K + k0 + sh;
#pragma unroll
                    for (int q = 0; q < 4; q++) {
                        float4 v = *(const float4*)(p + q * 4);
                        tmp[q * 4 + 0] = f2b(v.x); tmp[q * 4 + 1] = f2b(v.y);
                        tmp[q * 4 + 2] = f2b(v.z); tmp[q * 4 + 3] = f2b(v.w);
                    }
                } else {
#pragma unroll
                    for (int q = 0; q < 16; q++) tmp[q] = 0;
                }
            } else {
                const ushort* A = (const ushort*)Aptr;
                if (gr < M) {
                    const ushort* p = A + (size_t)gr * K + k0 + sh;
                    *(short8*)&tmp[0] = *(const short8*)(p);
                    *(short8*)&tmp[8] = *(const short8*)(p + 8);
                } else {
#pragma unroll
                    for (int q = 0; q < 16; q++) tmp[q] = 0;
                }
            }
            *(short8*)&As[sr][sh]     = *(short8*)&tmp[0];
            *(short8*)&As[sr][sh + 8] = *(short8*)&tmp[8];
        }
        {
#pragma unroll
            for (int t = 0; t < 2; t++) {
                int c = tid + t * 256;
                int row = c >> 2, q = c & 3;
                short8 v = *(const short8*)(WT + (size_t)row * K + k0 + q * 8);
                *(short8*)&Bs[row][q * 8] = v;
            }
        }
        __syncthreads();

        short8 af[4], bfv[4];
#pragma unroll
        for (int i = 0; i < 4; i++) af[i] = *(const short8*)&As[wr * 64 + i * 16 + lr][lk];
#pragma unroll
        for (int j = 0; j < 4; j++) bfv[j] = *(const short8*)&Bs[wc * 64 + j * 16 + lr][lk];
#pragma unroll
        for (int i = 0; i < 4; i++)
#pragma unroll
            for (int j = 0; j < 4; j++)
                acc[i][j] = __builtin_amdgcn_mfma_f32_16x16x32_bf16(af[i], bfv[j], acc[i][j], 0, 0, 0);
        __syncthreads();
    }

#pragma unroll
    for (int i = 0; i < 4; i++) {
#pragma unroll
        for (int r = 0; r < 4; r++) {
            int row = rowbase + wr * 64 + i * 16 + (lane >> 4) * 4 + r;
            if (row < M) {
                float sc = rowscale[row];
#pragma unroll
                for (int j = 0; j < 4; j++) {
                    int slice = wc * 2 + (j >> 1);
                    int f = (j & 1) * 16 + lr;
                    Hs[((size_t)slice * (M + 1) + row) * 32 + f] = f2b(acc[i][j][r] * sc);
                }
            }
        }
    }
}

// ---------------- edge-major segmented aggregation over 4 slices ----------------
// Wave owns a run of 8-edge groups; lanes: e8 = lane>>3 (edge in group), q = lane&7
// (8B = 4 feats). 2-deep colp prefetch; dinv loaded only at flush.

__global__ __launch_bounds__(256) void k_aggs(const ushort* __restrict__ hs,
                                              const int* __restrict__ goffs,
                                              const ushort* __restrict__ colp,
                                              const int* __restrict__ gnode,
                                              const float* __restrict__ dinv,
                                              const float* __restrict__ bias,
                                              ushort* __restrict__ outp, int n) {
    const int b = blockIdx.x;
    const int s = (b & 7) >> 1;                 // slice 0..3, pinned to XCD pair
    const int wid = threadIdx.x >> 6, lane = threadIdx.x & 63;
    const int e8 = lane >> 3, q = lane & 7;

    const int G = goffs[n];
    const int nranks = gridDim.x;
    const int rank = ((b >> 3) * 2 + (b & 1)) * 4 + wid;
    const int run = (G + nranks - 1) / nranks;
    int gs = rank * run;
    if (gs >= G) return;
    int ge = gs + run; if (ge > G) ge = G;
    if (gs > 0) {
        int pv = gnode[gs - 1];
        while (gs < ge && gnode[gs] == pv) gs++;   // skip previous wave's boundary node
        if (gs >= ge) return;
    }

    const ushort* hsl = hs + (size_t)s * (n + 1) * 32;
    const float4 bv = *(const float4*)(bias + s * 32 + q * 4);

    int g = gs;
    const ushort* cp = colp + (size_t)g * 8 + e8;
    const int* gp = gnode + g;
    int v = gp[0];
    uint sc0 = cp[0];       // current group's src
    uint sc1 = cp[8];       // next group's src
    float a0 = 0.f, a1 = 0.f, a2 = 0.f, a3 = 0.f;

    while (true) {
        uint sc2 = cp[16];          // 2-deep prefetch (sentinel groups exist)
        int v_n = gp[1];            // 1-deep
        uint2 pk = *(const uint2*)(hsl + (size_t)sc0 * 32 + q * 4);
        a0 += b2f_lo(pk.x); a1 += b2f_hi(pk.x);
        a2 += b2f_lo(pk.y); a3 += b2f_hi(pk.y);

        if (v_n != v) {   // wave-uniform node boundary -> flush
            float dv = dinv[v];
            float r0 = a0, r1 = a1, r2 = a2, r3 = a3;
#pragma unroll
            for (int off = 8; off <= 32; off <<= 1) {
                r0 += __shfl_xor(r0, off); r1 += __shfl_xor(r1, off);
                r2 += __shfl_xor(r2, off); r3 += __shfl_xor(r3, off);
            }
            r0 = fmaxf(fmaf(r0, dv, bv.x), 0.f);
            r1 = fmaxf(fmaf(r1, dv, bv.y), 0.f);
            r2 = fmaxf(fmaf(r2, dv, bv.z), 0.f);
            r3 = fmaxf(fmaf(r3, dv, bv.w), 0.f);
            if (lane < 8) {
                uint2 u;
                u.x = (uint)f2b(r0) | ((uint)f2b(r1) << 16);
                u.y = (uint)f2b(r2) | ((uint)f2b(r3) << 16);
                *(uint2*)(outp + (size_t)v * 128 + s * 32 + q * 4) = u;
            }
            if (g + 1 >= ge) break;
            v = v_n;
            a0 = a1 = a2 = a3 = 0.f;
        }
        g++; gp++; cp += 8;
        sc0 = sc1; sc1 = sc2;
    }
}

// ---------------- classifier + log_softmax (bf16 hidden input, row-major) ----------------

__global__ __launch_bounds__(256) void k_classify(const ushort* __restrict__ h,
                                                  const float* __restrict__ Wc,
                                                  const float* __restrict__ bc,
                                                  float* __restrict__ out, int n) {
    __shared__ float Ws[128 * 16];
    int tid = threadIdx.x;
#pragma unroll
    for (int t = 0; t < 8; t++) Ws[tid + 256 * t] = Wc[tid + 256 * t];
    __syncthreads();

    int wid = tid >> 6, lane = tid & 63;
    int v = blockIdx.x * 4 + wid;
    if (v >= n) return;

    int j = lane & 15, c = lane >> 4;
    const ushort* hv = h + (size_t)v * 128 + c * 32;
    float acc = 0.f;
#pragma unroll
    for (int t = 0; t < 16; t++) {
        uint pk = *(const uint*)(hv + t * 2);
        acc = fmaf(b2f_lo(pk), Ws[(c * 32 + t * 2 + 0) * 16 + j], acc);
        acc = fmaf(b2f_hi(pk), Ws[(c * 32 + t * 2 + 1) * 16 + j], acc);
    }
    acc += __shfl_xor(acc, 16);
    acc += __shfl_xor(acc, 32);
    acc += bc[j];

    float m = acc;
#pragma unroll
    for (int o = 8; o >= 1; o >>= 1) m = fmaxf(m, __shfl_xor(m, o));
    float sum = expf(acc - m);
#pragma unroll
    for (int o = 8; o >= 1; o >>= 1) sum += __shfl_xor(sum, o);
    if (lane < 16) out[(size_t)v * 16 + j] = acc - m - logf(sum);
}

// ---------------- launch ----------------

extern "C" void kernel_launch(void* const* d_in, const int* in_sizes, int n_in,
                              void* d_out, int out_size, void* d_ws, size_t ws_size,
                              hipStream_t stream) {
    const float* x  = (const float*)d_in[0];
    const int* eidx = (const int*)d_in[1];
    const float* W1 = (const float*)d_in[2];
    const float* b1 = (const float*)d_in[3];
    const float* W2 = (const float*)d_in[4];
    const float* b2 = (const float*)d_in[5];
    const float* Wc = (const float*)d_in[6];
    const float* bc = (const float*)d_in[7];
    float* out = (float*)d_out;

    const int N = in_sizes[0] / NFEAT;   // 50000 (< 65536 -> ushort node ids)
    const int E = in_sizes[1] / 2;       // 800000
    const int* src = eidx;
    const int* dst = eidx + E;

    char* p = (char*)d_ws;
    auto alloc = [&](size_t bytes) { char* r = p; p += (bytes + 255) & ~(size_t)255; return r; };
    int*    deg    = (int*)   alloc((size_t)N * 4);
    float*  dinv   = (float*) alloc((size_t)N * 4);
    int*    gcnt   = (int*)   alloc((size_t)N * 4);
    int*    goffs  = (int*)   alloc((size_t)(N + 1) * 4);
    int*    cursor = (int*)   alloc((size_t)N * 4);
    ushort* colp   = (ushort*)alloc(((size_t)E + 8ull * N + 32) * 2); // padded slots + 2 sentinel grps
    int*    gnode  = (int*)   alloc(((size_t)E / 8 + N + 2) * 4);
    int*    bsum   = (int*)   alloc((size_t)256 * 4);
    ushort* W1T    = (ushort*)alloc((size_t)128 * NFEAT * 2);
    ushort* W2T    = (ushort*)alloc((size_t)128 * NHID * 2);
    ushort* hs     = (ushort*)alloc((size_t)(N + 1) * NHID * 2);  // 4 slices x (N+1) x 32
    ushort* g1     = (ushort*)alloc((size_t)N * NHID * 2);        // agg1 out, row-major bf16
    ushort* g2     = (ushort*)alloc((size_t)N * NHID * 2);        // agg2 out, row-major bf16

    const int nb = (N + SCAN_BS - 1) / SCAN_BS;

    k_init_deg<<<(N + 255) / 256, 256, 0, stream>>>(deg, N);
    k_count<<<(E + 255) / 256, 256, 0, stream>>>(dst, E, deg);
    k_dinv<<<(N + 255) / 256, 256, 0, stream>>>(deg, dinv, gcnt, cursor, N);
    k_scan1<<<nb, SCAN_BS, 0, stream>>>(gcnt, goffs, bsum, N);
    k_scan2<<<1, 64, 0, stream>>>(bsum, goffs, nb, N);
    k_scan3<<<nb, SCAN_BS, 0, stream>>>(goffs, bsum, N);
    k_fill_edges<<<(E + 255) / 256, 256, 0, stream>>>(src, dst, E, goffs, cursor, colp);
    k_fill_tail<<<(N + 255) / 256, 256, 0, stream>>>(goffs, deg, colp, gnode, hs, N);

    k_tcast<<<(NFEAT * 128 + 255) / 256, 256, 0, stream>>>(W1, W1T, NFEAT);
    k_tcast<<<(NHID * 128 + 255) / 256, 256, 0, stream>>>(W2, W2T, NHID);

    const int gblocks = (N + 127) / 128;
    // layer 1
    k_gemm<1><<<gblocks, 256, 0, stream>>>(x, W1T, dinv, hs, N, NFEAT);
    k_aggs<<<AGG_BLOCKS, 256, 0, stream>>>(hs, goffs, colp, gnode, dinv, b1, g1, N);
    // layer 2
    k_gemm<0><<<gblocks, 256, 0, stream>>>(g1, W2T, dinv, hs, N, NHID);
    k_aggs<<<AGG_BLOCKS, 256, 0, stream>>>(hs, goffs, colp, gnode, dinv, b2, g2, N);
    // classifier
    k_classify<<<(N + 3) / 4, 256, 0, stream>>>(g2, Wc, bc, out, N);
}

// Round 8
// 266.639 us; speedup vs baseline: 1.2168x; 1.0350x over previous
//
#include <hip/hip_runtime.h>
#include <math.h>

#define NFEAT 512
#define NHID  128
#define NCLASS 16
#define SCAN_BS 512
#define AGG_BLOCKS 2048   // multiple of 8; slice=(b&7)>>1; rank count == AGG_BLOCKS

typedef __attribute__((ext_vector_type(8))) short short8;
typedef __attribute__((ext_vector_type(4))) float f32x4;

static __device__ __forceinline__ ushort f2b(float f) {
    union { float f; uint u; } v; v.f = f;
    uint r = v.u + 0x7FFFu + ((v.u >> 16) & 1u);   // round-to-nearest-even
    return (ushort)(r >> 16);
}
static __device__ __forceinline__ float b2f_lo(uint bits) {
    union { uint u; float f; } v; v.u = bits << 16; return v.f;
}
static __device__ __forceinline__ float b2f_hi(uint bits) {
    union { uint u; float f; } v; v.u = bits & 0xffff0000u; return v.f;
}

// ---------------- CSR build (group-padded, groups of 8 slots, meta-in-colp) -------------
// colp32[slot] = src(16b) | meta(16b);  meta = dst+1 on ALL slots of a node's LAST group,
// 0 otherwise. Sentinel groups after G: src=n (zero row), meta=0.

__global__ void k_init_deg(int* __restrict__ deg, int n) {
    int i = blockIdx.x * blockDim.x + threadIdx.x;
    if (i < n) deg[i] = 1;  // self-loop
}

__global__ void k_count(const int* __restrict__ dst, int e, int* __restrict__ deg) {
    int i = blockIdx.x * blockDim.x + threadIdx.x;
    if (i < e) atomicAdd(&deg[dst[i]], 1);
}

__global__ void k_dinv(const int* __restrict__ deg, float* __restrict__ dinv,
                       int* __restrict__ gcnt, int* __restrict__ cursor, int n) {
    int i = blockIdx.x * blockDim.x + threadIdx.x;
    if (i < n) {
        dinv[i] = rsqrtf((float)deg[i]);
        gcnt[i] = (deg[i] + 7) >> 3;
        cursor[i] = 0;
    }
}

__global__ void k_scan1(const int* __restrict__ in, int* __restrict__ offs,
                        int* __restrict__ bsum, int n) {
    __shared__ int s[SCAN_BS];
    int t = threadIdx.x;
    int i = blockIdx.x * SCAN_BS + t;
    int v = (i < n) ? in[i] : 0;
    s[t] = v;
    for (int off = 1; off < SCAN_BS; off <<= 1) {
        __syncthreads();
        int x = (t >= off) ? s[t - off] : 0;
        __syncthreads();
        s[t] += x;
    }
    __syncthreads();
    if (i < n) offs[i] = s[t] - v;
    if (t == SCAN_BS - 1) bsum[blockIdx.x] = s[t];
}

__global__ void k_scan2(int* __restrict__ bsum, int* __restrict__ offs, int nb, int n) {
    if (threadIdx.x == 0 && blockIdx.x == 0) {
        int run = 0;
        for (int b = 0; b < nb; b++) { int x = bsum[b]; bsum[b] = run; run += x; }
        offs[n] = run;   // = total groups G
    }
}

__global__ void k_scan3(int* __restrict__ offs, const int* __restrict__ bsum, int n) {
    int i = blockIdx.x * SCAN_BS + threadIdx.x;
    if (i < n) offs[i] += bsum[blockIdx.x];
}

__global__ void k_fill_edges(const int* __restrict__ src, const int* __restrict__ dst, int e,
                             const int* __restrict__ goffs, int* __restrict__ cursor,
                             uint* __restrict__ colp32) {
    int i = blockIdx.x * blockDim.x + threadIdx.x;
    if (i < e) {
        int d = dst[i];
        int p = atomicAdd(&cursor[d], 1);
        colp32[(size_t)goffs[d] * 8 + p] = (uint)src[i];   // meta 0
    }
}

// self-loop slot, pad slots, last-group meta, sentinel groups, zero sentinel hs rows
__global__ void k_fill_tail(const int* __restrict__ goffs, const int* __restrict__ deg,
                            uint* __restrict__ colp32, ushort* __restrict__ hs, int n) {
    int i = blockIdx.x * blockDim.x + threadIdx.x;
    if (i < 128) {  // zero sentinel row (node n) of each of the 4 slices
        int s = i >> 5, f = i & 31;
        hs[((size_t)s * (n + 1) + n) * 32 + f] = 0;
    }
    if (i < n) {
        int g0 = goffs[i], g1 = goffs[i + 1];
        size_t base = (size_t)g0 * 8;
        int d = deg[i];
        int slots = (g1 - g0) * 8;
        colp32[base + d - 1] = (uint)i;                        // self-loop
        for (int p = d; p < slots; p++) colp32[base + p] = (uint)n;  // pad -> zero row
        uint meta = (uint)(i + 1) << 16;
        for (int k = slots - 8; k < slots; k++) colp32[base + k] |= meta;
        if (i == 0) {
            int G = goffs[n];
            for (int k = 0; k < 32; k++) colp32[(size_t)G * 8 + k] = (uint)n;  // 4 sentinel grps
        }
    }
}

// per-rank start group (skip leading groups belonging to previous rank's boundary node)
__global__ void k_rankstart(const uint* __restrict__ colp32, const int* __restrict__ goffs,
                            int* __restrict__ rankgs, int n) {
    int r = blockIdx.x * blockDim.x + threadIdx.x;
    if (r >= AGG_BLOCKS) return;
    int G = goffs[n];
    int run = (G + AGG_BLOCKS - 1) / AGG_BLOCKS;
    int g = r * run;
    int ge = g + run; if (ge > G) ge = G;
    if (g >= G) { rankgs[r] = -1; return; }
    if (g > 0) {
        while (g < ge && !(colp32[(size_t)(g - 1) * 8] >> 16)) g++;  // mid-node -> skip
        if (g >= ge) { rankgs[r] = -1; return; }
    }
    rankgs[r] = g;
}

// ---------------- weight transpose+cast (both layers in one launch) ----------------

__global__ void k_tcast(const float* __restrict__ W1, const float* __restrict__ W2,
                        ushort* __restrict__ W1T, ushort* __restrict__ W2T) {
    int idx = blockIdx.x * 256 + threadIdx.x;
    if (idx < NFEAT * 128) {
        int k = idx >> 7, c = idx & 127;
        W1T[(size_t)c * NFEAT + k] = f2b(W1[idx]);
    } else {
        int j = idx - NFEAT * 128;
        if (j < NHID * 128) {
            int k = j >> 7, c = j & 127;
            W2T[(size_t)c * NHID + k] = f2b(W2[j]);
        }
    }
}

// ---------------- bf16 MFMA GEMM -> 4-slice output ----------------
// Hs layout: [slice(4)][node(M+1)][32 feats] bf16, pre-scaled by rowscale[row].

template<int A_F32>
__global__ __launch_bounds__(256) void k_gemm(const void* __restrict__ Aptr,
                                              const ushort* __restrict__ WT,
                                              const float* __restrict__ rowscale,
                                              ushort* __restrict__ Hs, int M, int K) {
    __shared__ ushort As[128][40];  // pad 40: <=2-way bank conflict (free)
    __shared__ ushort Bs[128][40];

    const int tid = threadIdx.x;
    const int wid = tid >> 6, lane = tid & 63;
    const int wr = wid >> 1, wc = wid & 1;
    const int lr = lane & 15, lk = (lane >> 4) * 8;
    const int rowbase = blockIdx.x * 128;

    f32x4 acc[4][4];
#pragma unroll
    for (int i = 0; i < 4; i++)
#pragma unroll
        for (int j = 0; j < 4; j++) acc[i][j] = (f32x4)0.f;

    const int sr = tid >> 1;
    const int sh = (tid & 1) * 16;

    for (int k0 = 0; k0 < K; k0 += 32) {
        {
            int gr = rowbase + sr;
            ushort tmp[16];
            if (A_F32) {
                const float* A = (const float*)Aptr;
                if (gr < M) {
                    const float* p = A + (size_t)gr * K + k0 + sh;
#pragma unroll
                    for (int q = 0; q < 4; q++) {
                        float4 v = *(const float4*)(p + q * 4);
                        tmp[q * 4 + 0] = f2b(v.x); tmp[q * 4 + 1] = f2b(v.y);
                        tmp[q * 4 + 2] = f2b(v.z); tmp[q * 4 + 3] = f2b(v.w);
                    }
                } else {
#pragma unroll
                    for (int q = 0; q < 16; q++) tmp[q] = 0;
                }
            } else {
                const ushort* A = (const ushort*)Aptr;
                if (gr < M) {
                    const ushort* p = A + (size_t)gr * K + k0 + sh;
                    *(short8*)&tmp[0] = *(const short8*)(p);
                    *(short8*)&tmp[8] = *(const short8*)(p + 8);
                } else {
#pragma unroll
                    for (int q = 0; q < 16; q++) tmp[q] = 0;
                }
            }
            *(short8*)&As[sr][sh]     = *(short8*)&tmp[0];
            *(short8*)&As[sr][sh + 8] = *(short8*)&tmp[8];
        }
        {
#pragma unroll
            for (int t = 0; t < 2; t++) {
                int c = tid + t * 256;
                int row = c >> 2, q = c & 3;
                short8 v = *(const short8*)(WT + (size_t)row * K + k0 + q * 8);
                *(short8*)&Bs[row][q * 8] = v;
            }
        }
        __syncthreads();

        short8 af[4], bfv[4];
#pragma unroll
        for (int i = 0; i < 4; i++) af[i] = *(const short8*)&As[wr * 64 + i * 16 + lr][lk];
#pragma unroll
        for (int j = 0; j < 4; j++) bfv[j] = *(const short8*)&Bs[wc * 64 + j * 16 + lr][lk];
#pragma unroll
        for (int i = 0; i < 4; i++)
#pragma unroll
            for (int j = 0; j < 4; j++)
                acc[i][j] = __builtin_amdgcn_mfma_f32_16x16x32_bf16(af[i], bfv[j], acc[i][j], 0, 0, 0);
        __syncthreads();
    }

#pragma unroll
    for (int i = 0; i < 4; i++) {
#pragma unroll
        for (int r = 0; r < 4; r++) {
            int row = rowbase + wr * 64 + i * 16 + (lane >> 4) * 4 + r;
            if (row < M) {
                float sc = rowscale[row];
#pragma unroll
                for (int j = 0; j < 4; j++) {
                    int slice = wc * 2 + (j >> 1);
                    int f = (j & 1) * 16 + lr;
                    Hs[((size_t)slice * (M + 1) + row) * 32 + f] = f2b(acc[i][j][r] * sc);
                }
            }
        }
    }
}

// ---------------- edge-major segmented aggregation, 2-deep gather pipeline ----------------
// Wave owns a run of 8-edge groups; lanes: e8 = lane>>3, q = lane&7 (8B = 4 feats).
// colp32 word = src | (dst+1)<<16 on last group of node. 3-deep colp, 2-deep gather,
// dinv prefetched with the meta word.

__global__ __launch_bounds__(256) void k_aggs(const ushort* __restrict__ hs,
                                              const uint* __restrict__ colp32,
                                              const int* __restrict__ rankgs,
                                              const int* __restrict__ goffs,
                                              const float* __restrict__ dinv,
                                              const float* __restrict__ bias,
                                              ushort* __restrict__ outp, int n) {
    const int b = blockIdx.x;
    const int s = (b & 7) >> 1;                 // slice 0..3, pinned to XCD pair
    const int wid = threadIdx.x >> 6, lane = threadIdx.x & 63;
    const int e8 = lane >> 3, q = lane & 7;

    const int G = goffs[n];
    const int rank = ((b >> 3) * 2 + (b & 1)) * 4 + wid;
    const int run = (G + AGG_BLOCKS - 1) / AGG_BLOCKS;
    int gs = rankgs[rank];
    int ge = (rank + 1) * run; if (ge > G) ge = G;
    if (gs < 0 || gs >= ge) return;

    const ushort* hsl = hs + (size_t)s * (n + 1) * 32;
    const float4 bv = *(const float4*)(bias + s * 32 + q * 4);

    int g = gs;
    const uint* cp = colp32 + (size_t)g * 8 + e8;
    uint cw0 = cp[0], cw1 = cp[8], cw2 = cp[16];
    uint2 pk0 = *(const uint2*)(hsl + (size_t)(cw0 & 0xffffu) * 32 + q * 4);
    uint2 pk1 = *(const uint2*)(hsl + (size_t)(cw1 & 0xffffu) * 32 + q * 4);
    float fdv0 = (cw0 >> 16) ? dinv[(cw0 >> 16) - 1] : 0.f;
    float fdv1 = (cw1 >> 16) ? dinv[(cw1 >> 16) - 1] : 0.f;
    float a0 = 0.f, a1 = 0.f, a2 = 0.f, a3 = 0.f;

    while (true) {
        uint cw3 = cp[24];
        uint2 pk2 = *(const uint2*)(hsl + (size_t)(cw2 & 0xffffu) * 32 + q * 4);
        float fdv2 = (cw2 >> 16) ? dinv[(cw2 >> 16) - 1] : 0.f;

        a0 += b2f_lo(pk0.x); a1 += b2f_hi(pk0.x);
        a2 += b2f_lo(pk0.y); a3 += b2f_hi(pk0.y);

        if (cw0 >> 16) {   // wave-uniform node boundary -> flush
            int v = (int)(cw0 >> 16) - 1;
            float r0 = a0, r1 = a1, r2 = a2, r3 = a3;
#pragma unroll
            for (int off = 8; off <= 32; off <<= 1) {
                r0 += __shfl_xor(r0, off); r1 += __shfl_xor(r1, off);
                r2 += __shfl_xor(r2, off); r3 += __shfl_xor(r3, off);
            }
            r0 = fmaxf(fmaf(r0, fdv0, bv.x), 0.f);
            r1 = fmaxf(fmaf(r1, fdv0, bv.y), 0.f);
            r2 = fmaxf(fmaf(r2, fdv0, bv.z), 0.f);
            r3 = fmaxf(fmaf(r3, fdv0, bv.w), 0.f);
            if (lane < 8) {
                uint2 u;
                u.x = (uint)f2b(r0) | ((uint)f2b(r1) << 16);
                u.y = (uint)f2b(r2) | ((uint)f2b(r3) << 16);
                *(uint2*)(outp + (size_t)v * 128 + s * 32 + q * 4) = u;
            }
            if (g + 1 >= ge) break;
            a0 = a1 = a2 = a3 = 0.f;
        }
        g++; cp += 8;
        cw0 = cw1; cw1 = cw2; cw2 = cw3;
        pk0 = pk1; pk1 = pk2;
        fdv0 = fdv1; fdv1 = fdv2;
    }
}

// ---------------- classifier + log_softmax (bf16 hidden input, row-major) ----------------

__global__ __launch_bounds__(256) void k_classify(const ushort* __restrict__ h,
                                                  const float* __restrict__ Wc,
                                                  const float* __restrict__ bc,
                                                  float* __restrict__ out, int n) {
    __shared__ float Ws[128 * 16];
    int tid = threadIdx.x;
#pragma unroll
    for (int t = 0; t < 8; t++) Ws[tid + 256 * t] = Wc[tid + 256 * t];
    __syncthreads();

    int wid = tid >> 6, lane = tid & 63;
    int v = blockIdx.x * 4 + wid;
    if (v >= n) return;

    int j = lane & 15, c = lane >> 4;
    const ushort* hv = h + (size_t)v * 128 + c * 32;
    float acc = 0.f;
#pragma unroll
    for (int t = 0; t < 16; t++) {
        uint pk = *(const uint*)(hv + t * 2);
        acc = fmaf(b2f_lo(pk), Ws[(c * 32 + t * 2 + 0) * 16 + j], acc);
        acc = fmaf(b2f_hi(pk), Ws[(c * 32 + t * 2 + 1) * 16 + j], acc);
    }
    acc += __shfl_xor(acc, 16);
    acc += __shfl_xor(acc, 32);
    acc += bc[j];

    float m = acc;
#pragma unroll
    for (int o = 8; o >= 1; o >>= 1) m = fmaxf(m, __shfl_xor(m, o));
    float sum = expf(acc - m);
#pragma unroll
    for (int o = 8; o >= 1; o >>= 1) sum += __shfl_xor(sum, o);
    if (lane < 16) out[(size_t)v * 16 + j] = acc - m - logf(sum);
}

// ---------------- launch ----------------

extern "C" void kernel_launch(void* const* d_in, const int* in_sizes, int n_in,
                              void* d_out, int out_size, void* d_ws, size_t ws_size,
                              hipStream_t stream) {
    const float* x  = (const float*)d_in[0];
    const int* eidx = (const int*)d_in[1];
    const float* W1 = (const float*)d_in[2];
    const float* b1 = (const float*)d_in[3];
    const float* W2 = (const float*)d_in[4];
    const float* b2 = (const float*)d_in[5];
    const float* Wc = (const float*)d_in[6];
    const float* bc = (const float*)d_in[7];
    float* out = (float*)d_out;

    const int N = in_sizes[0] / NFEAT;   // 50000 (< 65536 -> ushort node ids)
    const int E = in_sizes[1] / 2;       // 800000
    const int* src = eidx;
    const int* dst = eidx + E;

    char* p = (char*)d_ws;
    auto alloc = [&](size_t bytes) { char* r = p; p += (bytes + 255) & ~(size_t)255; return r; };
    int*    deg    = (int*)   alloc((size_t)N * 4);
    float*  dinv   = (float*) alloc((size_t)N * 4);
    int*    gcnt   = (int*)   alloc((size_t)N * 4);
    int*    goffs  = (int*)   alloc((size_t)(N + 1) * 4);
    int*    cursor = (int*)   alloc((size_t)N * 4);
    uint*   colp32 = (uint*)  alloc(((size_t)E + 8ull * N + 32) * 4); // padded slots + 4 sentinel grps
    int*    rankgs = (int*)   alloc((size_t)AGG_BLOCKS * 4);
    int*    bsum   = (int*)   alloc((size_t)256 * 4);
    ushort* W1T    = (ushort*)alloc((size_t)128 * NFEAT * 2);
    ushort* W2T    = (ushort*)alloc((size_t)128 * NHID * 2);
    ushort* hs     = (ushort*)alloc((size_t)(N + 1) * NHID * 2);  // 4 slices x (N+1) x 32
    ushort* g1     = (ushort*)alloc((size_t)N * NHID * 2);        // agg1 out, row-major bf16
    ushort* g2     = (ushort*)alloc((size_t)N * NHID * 2);        // agg2 out, row-major bf16

    const int nb = (N + SCAN_BS - 1) / SCAN_BS;

    k_init_deg<<<(N + 255) / 256, 256, 0, stream>>>(deg, N);
    k_count<<<(E + 255) / 256, 256, 0, stream>>>(dst, E, deg);
    k_dinv<<<(N + 255) / 256, 256, 0, stream>>>(deg, dinv, gcnt, cursor, N);
    k_scan1<<<nb, SCAN_BS, 0, stream>>>(gcnt, goffs, bsum, N);
    k_scan2<<<1, 64, 0, stream>>>(bsum, goffs, nb, N);
    k_scan3<<<nb, SCAN_BS, 0, stream>>>(goffs, bsum, N);
    k_fill_edges<<<(E + 255) / 256, 256, 0, stream>>>(src, dst, E, goffs, cursor, colp32);
    k_fill_tail<<<(N + 255) / 256, 256, 0, stream>>>(goffs, deg, colp32, hs, N);
    k_rankstart<<<(AGG_BLOCKS + 255) / 256, 256, 0, stream>>>(colp32, goffs, rankgs, N);

    k_tcast<<<((NFEAT + NHID) * 128 + 255) / 256, 256, 0, stream>>>(W1, W2, W1T, W2T);

    const int gblocks = (N + 127) / 128;
    // layer 1
    k_gemm<1><<<gblocks, 256, 0, stream>>>(x, W1T, dinv, hs, N, NFEAT);
    k_aggs<<<AGG_BLOCKS, 256, 0, stream>>>(hs, colp32, rankgs, goffs, dinv, b1, g1, N);
    // layer 2
    k_gemm<0><<<gblocks, 256, 0, stream>>>(g1, W2T, dinv, hs, N, NHID);
    k_aggs<<<AGG_BLOCKS, 256, 0, stream>>>(hs, colp32, rankgs, goffs, dinv, b2, g2, N);
    // classifier
    k_classify<<<(N + 3) / 4, 256, 0, stream>>>(g2, Wc, bc, out, N);
}

// Round 9
// 261.632 us; speedup vs baseline: 1.2401x; 1.0191x over previous
//
#include <hip/hip_runtime.h>
#include <math.h>

#define NFEAT 512
#define NHID  128
#define NCLASS 16
#define SCAN_BS 512
#define AGG_BLOCKS 2048   // multiple of 8; slice=(b&7)>>1; 2048 ranks

typedef __attribute__((ext_vector_type(8))) short short8;
typedef __attribute__((ext_vector_type(4))) float f32x4;

static __device__ __forceinline__ ushort f2b(float f) {
    union { float f; uint u; } v; v.f = f;
    uint r = v.u + 0x7FFFu + ((v.u >> 16) & 1u);   // round-to-nearest-even
    return (ushort)(r >> 16);
}
static __device__ __forceinline__ float b2f_lo(uint bits) {
    union { uint u; float f; } v; v.u = bits << 16; return v.f;
}
static __device__ __forceinline__ float b2f_hi(uint bits) {
    union { uint u; float f; } v; v.u = bits & 0xffff0000u; return v.f;
}

// ---------------- init: deg=1 (self-loop) + weight transpose/cast, one launch ----------

__global__ void k_init_tcast(const float* __restrict__ W1, const float* __restrict__ W2,
                             ushort* __restrict__ W1T, ushort* __restrict__ W2T,
                             int* __restrict__ deg, int n) {
    int idx = blockIdx.x * 256 + threadIdx.x;
    if (idx < n) deg[idx] = 1;
    if (idx < NFEAT * 128) {
        int k = idx >> 7, c = idx & 127;
        W1T[(size_t)c * NFEAT + k] = f2b(W1[idx]);
    } else {
        int j = idx - NFEAT * 128;
        if (j < NHID * 128) {
            int k = j >> 7, c = j & 127;
            W2T[(size_t)c * NHID + k] = f2b(W2[j]);
        }
    }
}

__global__ void k_count(const int* __restrict__ dst, int e, int* __restrict__ deg) {
    int i = blockIdx.x * blockDim.x + threadIdx.x;
    if (i < e) atomicAdd(&deg[dst[i]], 1);
}

// scan1 fused with dinv/cursor init; scans gcnt = ceil(deg/8)
__global__ void k_scan1(const int* __restrict__ deg, float* __restrict__ dinv,
                        int* __restrict__ cursor, int* __restrict__ offs,
                        int* __restrict__ bsum, int n) {
    __shared__ int s[SCAN_BS];
    int t = threadIdx.x;
    int i = blockIdx.x * SCAN_BS + t;
    int d = (i < n) ? deg[i] : 0;
    if (i < n) { dinv[i] = rsqrtf((float)d); cursor[i] = 0; }
    int v = (i < n) ? ((d + 7) >> 3) : 0;
    s[t] = v;
    for (int off = 1; off < SCAN_BS; off <<= 1) {
        __syncthreads();
        int x = (t >= off) ? s[t - off] : 0;
        __syncthreads();
        s[t] += x;
    }
    __syncthreads();
    if (i < n) offs[i] = s[t] - v;
    if (t == SCAN_BS - 1) bsum[blockIdx.x] = s[t];
}

// wave-parallel scan of block sums (nb <= 128)
__global__ void k_scan2(int* __restrict__ bsum, int* __restrict__ offs, int nb, int n) {
    int lane = threadIdx.x;  // blockDim = 64
    int carry = 0;
    for (int base = 0; base < nb; base += 64) {
        int i = base + lane;
        int v = (i < nb) ? bsum[i] : 0;
        int orig = v;
        for (int off = 1; off < 64; off <<= 1) {
            int t = __shfl_up(v, off);
            if (lane >= off) v += t;
        }
        if (i < nb) bsum[i] = carry + v - orig;   // exclusive
        carry += __shfl(v, 63);
    }
    if (lane == 0) offs[n] = carry;   // = total groups G
}

__global__ void k_scan3(int* __restrict__ offs, const int* __restrict__ bsum, int n) {
    int i = blockIdx.x * SCAN_BS + threadIdx.x;
    if (i < n) offs[i] += bsum[blockIdx.x];
}

__global__ void k_fill_edges(const int* __restrict__ src, const int* __restrict__ dst, int e,
                             const int* __restrict__ goffs, int* __restrict__ cursor,
                             uint* __restrict__ colp32) {
    int i = blockIdx.x * blockDim.x + threadIdx.x;
    if (i < e) {
        int d = dst[i];
        int p = atomicAdd(&cursor[d], 1);
        colp32[(size_t)goffs[d] * 8 + p] = (uint)src[i];   // meta 0
    }
}

// self-loop slot, pad slots, last-group meta, sentinel groups, zero sentinel hs rows
__global__ void k_fill_tail(const int* __restrict__ goffs, const int* __restrict__ deg,
                            uint* __restrict__ colp32, ushort* __restrict__ hs, int n) {
    int i = blockIdx.x * blockDim.x + threadIdx.x;
    if (i < 128) {  // zero sentinel row (node n) of each of the 4 slices
        int s = i >> 5, f = i & 31;
        hs[((size_t)s * (n + 1) + n) * 32 + f] = 0;
    }
    if (i < n) {
        int g0 = goffs[i], g1 = goffs[i + 1];
        size_t base = (size_t)g0 * 8;
        int d = deg[i];
        int slots = (g1 - g0) * 8;
        colp32[base + d - 1] = (uint)i;                        // self-loop
        for (int p = d; p < slots; p++) colp32[base + p] = (uint)n;  // pad -> zero row
        uint meta = (uint)(i + 1) << 16;
        for (int k = slots - 8; k < slots; k++) colp32[base + k] |= meta;
        if (i == 0) {
            int G = goffs[n];
            for (int k = 0; k < 48; k++) colp32[(size_t)G * 8 + k] = (uint)n;  // 6 sentinel grps
        }
    }
}

// per-rank start group (skip leading groups belonging to previous rank's boundary node)
__global__ void k_rankstart(const uint* __restrict__ colp32, const int* __restrict__ goffs,
                            int* __restrict__ rankgs, int n) {
    int r = blockIdx.x * blockDim.x + threadIdx.x;
    if (r >= AGG_BLOCKS) return;
    int G = goffs[n];
    int run = (G + AGG_BLOCKS - 1) / AGG_BLOCKS;
    int g = r * run;
    int ge = g + run; if (ge > G) ge = G;
    if (g >= G) { rankgs[r] = -1; return; }
    if (g > 0) {
        while (g < ge && !(colp32[(size_t)(g - 1) * 8] >> 16)) g++;  // mid-node -> skip
        if (g >= ge) { rankgs[r] = -1; return; }
    }
    rankgs[r] = g;
}

// ---------------- bf16 MFMA GEMM, 64x128 tile -> 4-slice output ----------------
// 4 waves; wave wc owns output cols [wc*32, wc*32+32) = slice wc.
// Hs layout: [slice(4)][node(M+1)][32 feats] bf16, pre-scaled by rowscale[row].

template<int A_F32>
__global__ __launch_bounds__(256) void k_gemm(const void* __restrict__ Aptr,
                                              const ushort* __restrict__ WT,
                                              const float* __restrict__ rowscale,
                                              ushort* __restrict__ Hs, int M, int K) {
    __shared__ ushort As[64][40];   // pad 40: <=2-way bank conflict (free)
    __shared__ ushort Bs[128][40];

    const int tid = threadIdx.x;
    const int wc = tid >> 6, lane = tid & 63;
    const int lr = lane & 15, lk = (lane >> 4) * 8;
    const int rowbase = blockIdx.x * 64;

    f32x4 acc[4][2];
#pragma unroll
    for (int i = 0; i < 4; i++)
#pragma unroll
        for (int j = 0; j < 2; j++) acc[i][j] = (f32x4)0.f;

    const int sr = tid >> 2;        // staging row 0..63
    const int sh = (tid & 3) * 8;   // staging octet

    for (int k0 = 0; k0 < K; k0 += 32) {
        // ---- stage A 64x32 (cvt to bf16 if f32) ----
        {
            int gr = rowbase + sr;
            ushort tmp[8];
            if (A_F32) {
                const float* A = (const float*)Aptr;
                if (gr < M) {
                    const float* p = A + (size_t)gr * K + k0 + sh;
#pragma unroll
                    for (int q = 0; q < 2; q++) {
                        float4 v = *(const float4*)(p + q * 4);
                        tmp[q * 4 + 0] = f2b(v.x); tmp[q * 4 + 1] = f2b(v.y);
                        tmp[q * 4 + 2] = f2b(v.z); tmp[q * 4 + 3] = f2b(v.w);
                    }
                } else {
#pragma unroll
                    for (int q = 0; q < 8; q++) tmp[q] = 0;
                }
            } else {
                const ushort* A = (const ushort*)Aptr;
                if (gr < M) {
                    *(short8*)&tmp[0] = *(const short8*)(A + (size_t)gr * K + k0 + sh);
                } else {
#pragma unroll
                    for (int q = 0; q < 8; q++) tmp[q] = 0;
                }
            }
            *(short8*)&As[sr][sh] = *(short8*)&tmp[0];
        }
        // ---- stage B from WT[128][K]: Bs[col][k] ----
        {
#pragma unroll
            for (int t = 0; t < 2; t++) {
                int c = tid + t * 256;
                int row = c >> 2, q = c & 3;
                short8 v = *(const short8*)(WT + (size_t)row * K + k0 + q * 8);
                *(short8*)&Bs[row][q * 8] = v;
            }
        }
        __syncthreads();

        short8 af[4], bfv[2];
#pragma unroll
        for (int i = 0; i < 4; i++) af[i] = *(const short8*)&As[i * 16 + lr][lk];
#pragma unroll
        for (int j = 0; j < 2; j++) bfv[j] = *(const short8*)&Bs[wc * 32 + j * 16 + lr][lk];
#pragma unroll
        for (int i = 0; i < 4; i++)
#pragma unroll
            for (int j = 0; j < 2; j++)
                acc[i][j] = __builtin_amdgcn_mfma_f32_16x16x32_bf16(af[i], bfv[j], acc[i][j], 0, 0, 0);
        __syncthreads();
    }

#pragma unroll
    for (int i = 0; i < 4; i++) {
#pragma unroll
        for (int r = 0; r < 4; r++) {
            int row = rowbase + i * 16 + (lane >> 4) * 4 + r;
            if (row < M) {
                float sc = rowscale[row];
#pragma unroll
                for (int j = 0; j < 2; j++) {
                    int f = j * 16 + lr;
                    Hs[((size_t)wc * (M + 1) + row) * 32 + f] = f2b(acc[i][j][r] * sc);
                }
            }
        }
    }
}

// ---------------- edge-major segmented aggregation, 3-deep gather pipeline ----------------
// Wave owns a run of 8-edge groups; lanes: e8 = lane>>3, q = lane&7 (8B = 4 feats).
// colp32 word = src | (dst+1)<<16 on last group of node. 4-deep colp, 3-deep gather.

__global__ __launch_bounds__(256) void k_aggs(const ushort* __restrict__ hs,
                                              const uint* __restrict__ colp32,
                                              const int* __restrict__ rankgs,
                                              const int* __restrict__ goffs,
                                              const float* __restrict__ dinv,
                                              const float* __restrict__ bias,
                                              ushort* __restrict__ outp, int n) {
    const int b = blockIdx.x;
    const int s = (b & 7) >> 1;                 // slice 0..3, pinned to XCD pair
    const int wid = threadIdx.x >> 6, lane = threadIdx.x & 63;
    const int e8 = lane >> 3, q = lane & 7;

    const int G = goffs[n];
    const int rank = ((b >> 3) * 2 + (b & 1)) * 4 + wid;
    const int run = (G + AGG_BLOCKS - 1) / AGG_BLOCKS;
    int gs = rankgs[rank];
    int ge = (rank + 1) * run; if (ge > G) ge = G;
    if (gs < 0 || gs >= ge) return;

    const ushort* hsl = hs + (size_t)s * (n + 1) * 32;
    const float4 bv = *(const float4*)(bias + s * 32 + q * 4);

    int g = gs;
    const uint* cp = colp32 + (size_t)g * 8 + e8;
    uint cw0 = cp[0], cw1 = cp[8], cw2 = cp[16], cw3 = cp[24];
    uint2 pk0 = *(const uint2*)(hsl + (size_t)(cw0 & 0xffffu) * 32 + q * 4);
    uint2 pk1 = *(const uint2*)(hsl + (size_t)(cw1 & 0xffffu) * 32 + q * 4);
    uint2 pk2 = *(const uint2*)(hsl + (size_t)(cw2 & 0xffffu) * 32 + q * 4);
    float fdv0 = (cw0 >> 16) ? dinv[(cw0 >> 16) - 1] : 0.f;
    float fdv1 = (cw1 >> 16) ? dinv[(cw1 >> 16) - 1] : 0.f;
    float fdv2 = (cw2 >> 16) ? dinv[(cw2 >> 16) - 1] : 0.f;
    float a0 = 0.f, a1 = 0.f, a2 = 0.f, a3 = 0.f;

    while (true) {
        uint cw4 = cp[32];
        uint2 pk3 = *(const uint2*)(hsl + (size_t)(cw3 & 0xffffu) * 32 + q * 4);
        float fdv3 = (cw3 >> 16) ? dinv[(cw3 >> 16) - 1] : 0.f;

        a0 += b2f_lo(pk0.x); a1 += b2f_hi(pk0.x);
        a2 += b2f_lo(pk0.y); a3 += b2f_hi(pk0.y);

        if (cw0 >> 16) {   // wave-uniform node boundary -> flush
            int v = (int)(cw0 >> 16) - 1;
            float r0 = a0, r1 = a1, r2 = a2, r3 = a3;
#pragma unroll
            for (int off = 8; off <= 32; off <<= 1) {
                r0 += __shfl_xor(r0, off); r1 += __shfl_xor(r1, off);
                r2 += __shfl_xor(r2, off); r3 += __shfl_xor(r3, off);
            }
            r0 = fmaxf(fmaf(r0, fdv0, bv.x), 0.f);
            r1 = fmaxf(fmaf(r1, fdv0, bv.y), 0.f);
            r2 = fmaxf(fmaf(r2, fdv0, bv.z), 0.f);
            r3 = fmaxf(fmaf(r3, fdv0, bv.w), 0.f);
            if (lane < 8) {
                uint2 u;
                u.x = (uint)f2b(r0) | ((uint)f2b(r1) << 16);
                u.y = (uint)f2b(r2) | ((uint)f2b(r3) << 16);
                *(uint2*)(outp + (size_t)v * 128 + s * 32 + q * 4) = u;
            }
            if (g + 1 >= ge) break;
            a0 = a1 = a2 = a3 = 0.f;
        }
        g++; cp += 8;
        cw0 = cw1; cw1 = cw2; cw2 = cw3; cw3 = cw4;
        pk0 = pk1; pk1 = pk2; pk2 = pk3;
        fdv0 = fdv1; fdv1 = fdv2; fdv2 = fdv3;
    }
}

// ---------------- classifier + log_softmax (bf16 hidden input, row-major) ----------------

__global__ __launch_bounds__(256) void k_classify(const ushort* __restrict__ h,
                                                  const float* __restrict__ Wc,
                                                  const float* __restrict__ bc,
                                                  float* __restrict__ out, int n) {
    __shared__ float Ws[128 * 16];
    int tid = threadIdx.x;
#pragma unroll
    for (int t = 0; t < 8; t++) Ws[tid + 256 * t] = Wc[tid + 256 * t];
    __syncthreads();

    int wid = tid >> 6, lane = tid & 63;
    int v = blockIdx.x * 4 + wid;
    if (v >= n) return;

    int j = lane & 15, c = lane >> 4;
    const ushort* hv = h + (size_t)v * 128 + c * 32;
    float acc = 0.f;
#pragma unroll
    for (int t = 0; t < 16; t++) {
        uint pk = *(const uint*)(hv + t * 2);
        acc = fmaf(b2f_lo(pk), Ws[(c * 32 + t * 2 + 0) * 16 + j], acc);
        acc = fmaf(b2f_hi(pk), Ws[(c * 32 + t * 2 + 1) * 16 + j], acc);
    }
    acc += __shfl_xor(acc, 16);
    acc += __shfl_xor(acc, 32);
    acc += bc[j];

    float m = acc;
#pragma unroll
    for (int o = 8; o >= 1; o >>= 1) m = fmaxf(m, __shfl_xor(m, o));
    float sum = expf(acc - m);
#pragma unroll
    for (int o = 8; o >= 1; o >>= 1) sum += __shfl_xor(sum, o);
    if (lane < 16) out[(size_t)v * 16 + j] = acc - m - logf(sum);
}

// ---------------- launch ----------------

extern "C" void kernel_launch(void* const* d_in, const int* in_sizes, int n_in,
                              void* d_out, int out_size, void* d_ws, size_t ws_size,
                              hipStream_t stream) {
    const float* x  = (const float*)d_in[0];
    const int* eidx = (const int*)d_in[1];
    const float* W1 = (const float*)d_in[2];
    const float* b1 = (const float*)d_in[3];
    const float* W2 = (const float*)d_in[4];
    const float* b2 = (const float*)d_in[5];
    const float* Wc = (const float*)d_in[6];
    const float* bc = (const float*)d_in[7];
    float* out = (float*)d_out;

    const int N = in_sizes[0] / NFEAT;   // 50000 (< 65536 -> ushort node ids)
    const int E = in_sizes[1] / 2;       // 800000
    const int* src = eidx;
    const int* dst = eidx + E;

    char* p = (char*)d_ws;
    auto alloc = [&](size_t bytes) { char* r = p; p += (bytes + 255) & ~(size_t)255; return r; };
    int*    deg    = (int*)   alloc((size_t)N * 4);
    float*  dinv   = (float*) alloc((size_t)N * 4);
    int*    goffs  = (int*)   alloc((size_t)(N + 1) * 4);
    int*    cursor = (int*)   alloc((size_t)N * 4);
    uint*   colp32 = (uint*)  alloc(((size_t)E + 8ull * N + 64) * 4); // padded slots + 6 sentinel grps
    int*    rankgs = (int*)   alloc((size_t)AGG_BLOCKS * 4);
    int*    bsum   = (int*)   alloc((size_t)256 * 4);
    ushort* W1T    = (ushort*)alloc((size_t)128 * NFEAT * 2);
    ushort* W2T    = (ushort*)alloc((size_t)128 * NHID * 2);
    ushort* hs     = (ushort*)alloc((size_t)(N + 1) * NHID * 2);  // 4 slices x (N+1) x 32
    ushort* g1     = (ushort*)alloc((size_t)N * NHID * 2);        // agg1 out, row-major bf16
    ushort* g2     = (ushort*)alloc((size_t)N * NHID * 2);        // agg2 out, row-major bf16

    const int nb = (N + SCAN_BS - 1) / SCAN_BS;

    k_init_tcast<<<((NFEAT + NHID) * 128 + 255) / 256, 256, 0, stream>>>(W1, W2, W1T, W2T, deg, N);
    k_count<<<(E + 255) / 256, 256, 0, stream>>>(dst, E, deg);
    k_scan1<<<nb, SCAN_BS, 0, stream>>>(deg, dinv, cursor, goffs, bsum, N);
    k_scan2<<<1, 64, 0, stream>>>(bsum, goffs, nb, N);
    k_scan3<<<nb, SCAN_BS, 0, stream>>>(goffs, bsum, N);
    k_fill_edges<<<(E + 255) / 256, 256, 0, stream>>>(src, dst, E, goffs, cursor, colp32);
    k_fill_tail<<<(N + 255) / 256, 256, 0, stream>>>(goffs, deg, colp32, hs, N);
    k_rankstart<<<(AGG_BLOCKS + 255) / 256, 256, 0, stream>>>(colp32, goffs, rankgs, N);

    const int gblocks = (N + 63) / 64;
    // layer 1
    k_gemm<1><<<gblocks, 256, 0, stream>>>(x, W1T, dinv, hs, N, NFEAT);
    k_aggs<<<AGG_BLOCKS, 256, 0, stream>>>(hs, colp32, rankgs, goffs, dinv, b1, g1, N);
    // layer 2
    k_gemm<0><<<gblocks, 256, 0, stream>>>(g1, W2T, dinv, hs, N, NHID);
    k_aggs<<<AGG_BLOCKS, 256, 0, stream>>>(hs, colp32, rankgs, goffs, dinv, b2, g2, N);
    // classifier
    k_classify<<<(N + 3) / 4, 256, 0, stream>>>(g2, Wc, bc, out, N);
}

// Round 10
// 260.631 us; speedup vs baseline: 1.2449x; 1.0038x over previous
//
#include <hip/hip_runtime.h>
#include <math.h>

#define NFEAT 512
#define NHID  128
#define NCLASS 16
#define SCAN_BS 512
#define AGG_BLOCKS 1024   // 256 blocks per slice (slice = b&3)
#define NSTREAMS 16384    // per slice: 256 blocks x 4 waves x 16 streams

typedef __attribute__((ext_vector_type(8))) short short8;
typedef __attribute__((ext_vector_type(4))) float f32x4;

static __device__ __forceinline__ ushort f2b(float f) {
    union { float f; uint u; } v; v.f = f;
    uint r = v.u + 0x7FFFu + ((v.u >> 16) & 1u);   // round-to-nearest-even
    return (ushort)(r >> 16);
}
static __device__ __forceinline__ float b2f_lo(uint bits) {
    union { uint u; float f; } v; v.u = bits << 16; return v.f;
}
static __device__ __forceinline__ float b2f_hi(uint bits) {
    union { uint u; float f; } v; v.u = bits & 0xffff0000u; return v.f;
}

// ---------------- init: deg=1 (self-loop) + weight transpose/cast ----------

__global__ void k_init_tcast(const float* __restrict__ W1, const float* __restrict__ W2,
                             ushort* __restrict__ W1T, ushort* __restrict__ W2T,
                             int* __restrict__ deg, int n) {
    int idx = blockIdx.x * 256 + threadIdx.x;
    if (idx < n) deg[idx] = 1;
    if (idx < NFEAT * 128) {
        int k = idx >> 7, c = idx & 127;
        W1T[(size_t)c * NFEAT + k] = f2b(W1[idx]);
    } else {
        int j = idx - NFEAT * 128;
        if (j < NHID * 128) {
            int k = j >> 7, c = j & 127;
            W2T[(size_t)c * NHID + k] = f2b(W2[j]);
        }
    }
}

__global__ void k_count(const int* __restrict__ dst, int e, int* __restrict__ deg) {
    int i = blockIdx.x * blockDim.x + threadIdx.x;
    if (i < e) atomicAdd(&deg[dst[i]], 1);
}

// scan deg (edge offsets, no padding) fused with dinv/cursor init
__global__ void k_scan1(const int* __restrict__ deg, float* __restrict__ dinv,
                        int* __restrict__ cursor, int* __restrict__ offs,
                        int* __restrict__ bsum, int n) {
    __shared__ int s[SCAN_BS];
    int t = threadIdx.x;
    int i = blockIdx.x * SCAN_BS + t;
    int d = (i < n) ? deg[i] : 0;
    if (i < n) { dinv[i] = rsqrtf((float)d); cursor[i] = 0; }
    s[t] = d;
    for (int off = 1; off < SCAN_BS; off <<= 1) {
        __syncthreads();
        int x = (t >= off) ? s[t - off] : 0;
        __syncthreads();
        s[t] += x;
    }
    __syncthreads();
    if (i < n) offs[i] = s[t] - d;
    if (t == SCAN_BS - 1) bsum[blockIdx.x] = s[t];
}

// wave-parallel scan of block sums (nb <= 128)
__global__ void k_scan2(int* __restrict__ bsum, int* __restrict__ offs, int nb, int n) {
    int lane = threadIdx.x;  // blockDim = 64
    int carry = 0;
    for (int base = 0; base < nb; base += 64) {
        int i = base + lane;
        int v = (i < nb) ? bsum[i] : 0;
        int orig = v;
        for (int off = 1; off < 64; off <<= 1) {
            int t = __shfl_up(v, off);
            if (lane >= off) v += t;
        }
        if (i < nb) bsum[i] = carry + v - orig;   // exclusive
        carry += __shfl(v, 63);
    }
    if (lane == 0) offs[n] = carry;   // = E + N
}

__global__ void k_scan3(int* __restrict__ offs, const int* __restrict__ bsum, int n) {
    int i = blockIdx.x * SCAN_BS + threadIdx.x;
    if (i < n) offs[i] += bsum[blockIdx.x];
}

// fill real edges (slots [eoffs[d], eoffs[d]+deg-1)) + per-node self/meta slot + pad words
// colp32[slot] = src(16b) | meta(16b); meta = dst+1 only on the LAST slot of each node
// (which is the self-loop slot). Disjoint writes -> one kernel.
__global__ void k_fill_edges(const int* __restrict__ src, const int* __restrict__ dst, int e,
                             const int* __restrict__ eoffs, int* __restrict__ cursor,
                             uint* __restrict__ colp32, int n, int S) {
    int i = blockIdx.x * blockDim.x + threadIdx.x;
    if (i < e) {
        int d = dst[i];
        int p = atomicAdd(&cursor[d], 1);
        colp32[eoffs[d] + p] = (uint)src[i];   // meta 0
    }
    if (i < n) {
        colp32[eoffs[i + 1] - 1] = (uint)i | ((uint)(i + 1) << 16);  // self-loop + boundary meta
    }
    if (i == 0) {
#pragma unroll
        for (int k = 0; k < 8; k++) colp32[S + k] = 0;   // prefetch pad (src 0, no meta)
    }
}

// per-stream start slot: first node-start >= r*len (node start <=> meta on slot-1)
__global__ void k_rankstart(const uint* __restrict__ colp32, int* __restrict__ rankgs, int S) {
    int r = blockIdx.x * blockDim.x + threadIdx.x;
    if (r >= NSTREAMS) return;
    int len = (S + NSTREAMS - 1) / NSTREAMS;
    int g = r * len;
    int ge = g + len; if (ge > S) ge = S;
    if (g >= S) { rankgs[r] = -1; return; }
    if (g > 0) {
        while (g < ge && !(colp32[g - 1] >> 16)) g++;
        if (g >= ge) { rankgs[r] = -1; return; }
    }
    rankgs[r] = g;
}

// ---------------- bf16 MFMA GEMM, 64x128 tile -> 4-slice output ----------------
// 4 waves; wave wc owns output cols [wc*32, wc*32+32) = slice wc.
// Hs layout: [slice(4)][node(M)][32 feats] bf16, pre-scaled by rowscale[row].

template<int A_F32>
__global__ __launch_bounds__(256) void k_gemm(const void* __restrict__ Aptr,
                                              const ushort* __restrict__ WT,
                                              const float* __restrict__ rowscale,
                                              ushort* __restrict__ Hs, int M, int K) {
    __shared__ ushort As[64][40];   // pad 40: <=2-way bank conflict (free)
    __shared__ ushort Bs[128][40];

    const int tid = threadIdx.x;
    const int wc = tid >> 6, lane = tid & 63;
    const int lr = lane & 15, lk = (lane >> 4) * 8;
    const int rowbase = blockIdx.x * 64;

    f32x4 acc[4][2];
#pragma unroll
    for (int i = 0; i < 4; i++)
#pragma unroll
        for (int j = 0; j < 2; j++) acc[i][j] = (f32x4)0.f;

    const int sr = tid >> 2;        // staging row 0..63
    const int sh = (tid & 3) * 8;   // staging octet

    for (int k0 = 0; k0 < K; k0 += 32) {
        {
            int gr = rowbase + sr;
            ushort tmp[8];
            if (A_F32) {
                const float* A = (const float*)Aptr;
                if (gr < M) {
                    const float* p = A + (size_t)gr * K + k0 + sh;
#pragma unroll
                    for (int q = 0; q < 2; q++) {
                        float4 v = *(const float4*)(p + q * 4);
                        tmp[q * 4 + 0] = f2b(v.x); tmp[q * 4 + 1] = f2b(v.y);
                        tmp[q * 4 + 2] = f2b(v.z); tmp[q * 4 + 3] = f2b(v.w);
                    }
                } else {
#pragma unroll
                    for (int q = 0; q < 8; q++) tmp[q] = 0;
                }
            } else {
                const ushort* A = (const ushort*)Aptr;
                if (gr < M) {
                    *(short8*)&tmp[0] = *(const short8*)(A + (size_t)gr * K + k0 + sh);
                } else {
#pragma unroll
                    for (int q = 0; q < 8; q++) tmp[q] = 0;
                }
            }
            *(short8*)&As[sr][sh] = *(short8*)&tmp[0];
        }
        {
#pragma unroll
            for (int t = 0; t < 2; t++) {
                int c = tid + t * 256;
                int row = c >> 2, q = c & 3;
                short8 v = *(const short8*)(WT + (size_t)row * K + k0 + q * 8);
                *(short8*)&Bs[row][q * 8] = v;
            }
        }
        __syncthreads();

        short8 af[4], bfv[2];
#pragma unroll
        for (int i = 0; i < 4; i++) af[i] = *(const short8*)&As[i * 16 + lr][lk];
#pragma unroll
        for (int j = 0; j < 2; j++) bfv[j] = *(const short8*)&Bs[wc * 32 + j * 16 + lr][lk];
#pragma unroll
        for (int i = 0; i < 4; i++)
#pragma unroll
            for (int j = 0; j < 2; j++)
                acc[i][j] = __builtin_amdgcn_mfma_f32_16x16x32_bf16(af[i], bfv[j], acc[i][j], 0, 0, 0);
        __syncthreads();
    }

#pragma unroll
    for (int i = 0; i < 4; i++) {
#pragma unroll
        for (int r = 0; r < 4; r++) {
            int row = rowbase + i * 16 + (lane >> 4) * 4 + r;
            if (row < M) {
                float sc = rowscale[row];
#pragma unroll
                for (int j = 0; j < 2; j++) {
                    int f = j * 16 + lr;
                    Hs[((size_t)wc * M + row) * 32 + f] = f2b(acc[i][j][r] * sc);
                }
            }
        }
    }
}

// ---------------- stream-parallel segmented aggregation ----------------
// 16 streams per wave (4 lanes x 16B each); stream processes its slot range
// sequentially: gather row slice (uint4 = 8 feats/lane), accumulate in f32,
// flush at node boundary (meta word) with NO cross-lane reduce.

__global__ __launch_bounds__(256) void k_aggs(const ushort* __restrict__ hs,
                                              const uint* __restrict__ colp32,
                                              const int* __restrict__ rankgs,
                                              const float* __restrict__ dinv,
                                              const float* __restrict__ bias,
                                              ushort* __restrict__ outp, int n, int S) {
    const int b = blockIdx.x;
    const int s = b & 3;                          // slice, pinned to XCDs {s, s+4}
    const int wid = threadIdx.x >> 6, lane = threadIdx.x & 63;
    const int st16 = lane >> 2, q = lane & 3;     // stream-in-wave, feat-quad (16B)
    const int stream = (((b >> 2) << 2) + wid) * 16 + st16;
    const int len = (S + NSTREAMS - 1) / NSTREAMS;
    int gs = rankgs[stream];
    int ge = (stream + 1) * len; if (ge > S) ge = S;
    bool alive = (gs >= 0);
    int g = alive ? gs : 0;

    const ushort* hsl = hs + (size_t)s * n * 32;
    const float4 bv0 = *(const float4*)(bias + s * 32 + q * 8);
    const float4 bv1 = *(const float4*)(bias + s * 32 + q * 8 + 4);

    const uint* cp = colp32 + g;
    uint cw0 = cp[0], cw1 = cp[1], cw2 = cp[2];
    uint4 pk0 = *(const uint4*)(hsl + (size_t)(cw0 & 0xffffu) * 32 + q * 8);
    uint4 pk1 = *(const uint4*)(hsl + (size_t)(cw1 & 0xffffu) * 32 + q * 8);
    float fdv0 = (cw0 >> 16) ? dinv[(cw0 >> 16) - 1] : 0.f;
    float fdv1 = (cw1 >> 16) ? dinv[(cw1 >> 16) - 1] : 0.f;
    float a0 = 0.f, a1 = 0.f, a2 = 0.f, a3 = 0.f;
    float a4 = 0.f, a5 = 0.f, a6 = 0.f, a7 = 0.f;

    while (__any(alive)) {
        if (alive) {
            uint cw3 = cp[3];
            uint4 pk2 = *(const uint4*)(hsl + (size_t)(cw2 & 0xffffu) * 32 + q * 8);
            float fdv2 = (cw2 >> 16) ? dinv[(cw2 >> 16) - 1] : 0.f;

            a0 += b2f_lo(pk0.x); a1 += b2f_hi(pk0.x);
            a2 += b2f_lo(pk0.y); a3 += b2f_hi(pk0.y);
            a4 += b2f_lo(pk0.z); a5 += b2f_hi(pk0.z);
            a6 += b2f_lo(pk0.w); a7 += b2f_hi(pk0.w);

            if (cw0 >> 16) {   // node boundary (per-stream, exec-masked)
                int v = (int)(cw0 >> 16) - 1;
                float r0 = fmaxf(fmaf(a0, fdv0, bv0.x), 0.f);
                float r1 = fmaxf(fmaf(a1, fdv0, bv0.y), 0.f);
                float r2 = fmaxf(fmaf(a2, fdv0, bv0.z), 0.f);
                float r3 = fmaxf(fmaf(a3, fdv0, bv0.w), 0.f);
                float r4 = fmaxf(fmaf(a4, fdv0, bv1.x), 0.f);
                float r5 = fmaxf(fmaf(a5, fdv0, bv1.y), 0.f);
                float r6 = fmaxf(fmaf(a6, fdv0, bv1.z), 0.f);
                float r7 = fmaxf(fmaf(a7, fdv0, bv1.w), 0.f);
                uint4 u;
                u.x = (uint)f2b(r0) | ((uint)f2b(r1) << 16);
                u.y = (uint)f2b(r2) | ((uint)f2b(r3) << 16);
                u.z = (uint)f2b(r4) | ((uint)f2b(r5) << 16);
                u.w = (uint)f2b(r6) | ((uint)f2b(r7) << 16);
                *(uint4*)(outp + (size_t)v * 128 + s * 32 + q * 8) = u;
                a0 = a1 = a2 = a3 = a4 = a5 = a6 = a7 = 0.f;
                if (g + 1 >= ge) alive = false;
            }
            g++; cp++;
            cw0 = cw1; cw1 = cw2; cw2 = cw3;
            pk0 = pk1; pk1 = pk2;
            fdv0 = fdv1; fdv1 = fdv2;
        }
    }
}

// ---------------- classifier + log_softmax (bf16 hidden input, row-major) ----------------

__global__ __launch_bounds__(256) void k_classify(const ushort* __restrict__ h,
                                                  const float* __restrict__ Wc,
                                                  const float* __restrict__ bc,
                                                  float* __restrict__ out, int n) {
    __shared__ float Ws[128 * 16];
    int tid = threadIdx.x;
#pragma unroll
    for (int t = 0; t < 8; t++) Ws[tid + 256 * t] = Wc[tid + 256 * t];
    __syncthreads();

    int wid = tid >> 6, lane = tid & 63;
    int v = blockIdx.x * 4 + wid;
    if (v >= n) return;

    int j = lane & 15, c = lane >> 4;
    const ushort* hv = h + (size_t)v * 128 + c * 32;
    float acc = 0.f;
#pragma unroll
    for (int t = 0; t < 16; t++) {
        uint pk = *(const uint*)(hv + t * 2);
        acc = fmaf(b2f_lo(pk), Ws[(c * 32 + t * 2 + 0) * 16 + j], acc);
        acc = fmaf(b2f_hi(pk), Ws[(c * 32 + t * 2 + 1) * 16 + j], acc);
    }
    acc += __shfl_xor(acc, 16);
    acc += __shfl_xor(acc, 32);
    acc += bc[j];

    float m = acc;
#pragma unroll
    for (int o = 8; o >= 1; o >>= 1) m = fmaxf(m, __shfl_xor(m, o));
    float sum = expf(acc - m);
#pragma unroll
    for (int o = 8; o >= 1; o >>= 1) sum += __shfl_xor(sum, o);
    if (lane < 16) out[(size_t)v * 16 + j] = acc - m - logf(sum);
}

// ---------------- launch ----------------

extern "C" void kernel_launch(void* const* d_in, const int* in_sizes, int n_in,
                              void* d_out, int out_size, void* d_ws, size_t ws_size,
                              hipStream_t stream) {
    const float* x  = (const float*)d_in[0];
    const int* eidx = (const int*)d_in[1];
    const float* W1 = (const float*)d_in[2];
    const float* b1 = (const float*)d_in[3];
    const float* W2 = (const float*)d_in[4];
    const float* b2 = (const float*)d_in[5];
    const float* Wc = (const float*)d_in[6];
    const float* bc = (const float*)d_in[7];
    float* out = (float*)d_out;

    const int N = in_sizes[0] / NFEAT;   // 50000 (< 65536 -> 16-bit node ids)
    const int E = in_sizes[1] / 2;       // 800000
    const int S = E + N;                 // total slots (no padding)
    const int* src = eidx;
    const int* dst = eidx + E;

    char* p = (char*)d_ws;
    auto alloc = [&](size_t bytes) { char* r = p; p += (bytes + 255) & ~(size_t)255; return r; };
    int*    deg    = (int*)   alloc((size_t)N * 4);
    float*  dinv   = (float*) alloc((size_t)N * 4);
    int*    eoffs  = (int*)   alloc((size_t)(N + 1) * 4);
    int*    cursor = (int*)   alloc((size_t)N * 4);
    uint*   colp32 = (uint*)  alloc(((size_t)S + 16) * 4);
    int*    rankgs = (int*)   alloc((size_t)NSTREAMS * 4);
    int*    bsum   = (int*)   alloc((size_t)256 * 4);
    ushort* W1T    = (ushort*)alloc((size_t)128 * NFEAT * 2);
    ushort* W2T    = (ushort*)alloc((size_t)128 * NHID * 2);
    ushort* hs     = (ushort*)alloc((size_t)N * NHID * 2);   // 4 slices x N x 32
    ushort* g1     = (ushort*)alloc((size_t)N * NHID * 2);   // agg1 out, row-major bf16
    ushort* g2     = (ushort*)alloc((size_t)N * NHID * 2);   // agg2 out, row-major bf16

    const int nb = (N + SCAN_BS - 1) / SCAN_BS;

    k_init_tcast<<<((NFEAT + NHID) * 128 + 255) / 256, 256, 0, stream>>>(W1, W2, W1T, W2T, deg, N);
    k_count<<<(E + 255) / 256, 256, 0, stream>>>(dst, E, deg);
    k_scan1<<<nb, SCAN_BS, 0, stream>>>(deg, dinv, cursor, eoffs, bsum, N);
    k_scan2<<<1, 64, 0, stream>>>(bsum, eoffs, nb, N);
    k_scan3<<<nb, SCAN_BS, 0, stream>>>(eoffs, bsum, N);
    k_fill_edges<<<(E + 255) / 256, 256, 0, stream>>>(src, dst, E, eoffs, cursor, colp32, N, S);
    k_rankstart<<<(NSTREAMS + 255) / 256, 256, 0, stream>>>(colp32, rankgs, S);

    const int gblocks = (N + 63) / 64;
    // layer 1
    k_gemm<1><<<gblocks, 256, 0, stream>>>(x, W1T, dinv, hs, N, NFEAT);
    k_aggs<<<AGG_BLOCKS, 256, 0, stream>>>(hs, colp32, rankgs, dinv, b1, g1, N, S);
    // layer 2
    k_gemm<0><<<gblocks, 256, 0, stream>>>(g1, W2T, dinv, hs, N, NHID);
    k_aggs<<<AGG_BLOCKS, 256, 0, stream>>>(hs, colp32, rankgs, dinv, b2, g2, N, S);
    // classifier
    k_classify<<<(N + 3) / 4, 256, 0, stream>>>(g2, Wc, bc, out, N);
}

// Round 11
// 227.695 us; speedup vs baseline: 1.4250x; 1.1446x over previous
//
#include <hip/hip_runtime.h>
#include <math.h>

#define NFEAT 512
#define NHID  128
#define NCLASS 16
#define SCAN_BS 512
#define AGG_BLOCKS 1024   // 256 blocks per slice (slice = b&3)
#define NSTREAMS 16384    // per slice: 256 blocks x 4 waves x 16 streams

typedef __attribute__((ext_vector_type(8))) short short8;
typedef __attribute__((ext_vector_type(4))) float f32x4;

static __device__ __forceinline__ ushort f2b(float f) {
    union { float f; uint u; } v; v.f = f;
    uint r = v.u + 0x7FFFu + ((v.u >> 16) & 1u);   // round-to-nearest-even
    return (ushort)(r >> 16);
}
static __device__ __forceinline__ float b2f_lo(uint bits) {
    union { uint u; float f; } v; v.u = bits << 16; return v.f;
}
static __device__ __forceinline__ float b2f_hi(uint bits) {
    union { uint u; float f; } v; v.u = bits & 0xffff0000u; return v.f;
}

// ---------------- init: deg=1 (self-loop) + weight transpose/cast ----------

__global__ void k_init_tcast(const float* __restrict__ W1, const float* __restrict__ W2,
                             ushort* __restrict__ W1T, ushort* __restrict__ W2T,
                             int* __restrict__ deg, int n) {
    int idx = blockIdx.x * 256 + threadIdx.x;
    if (idx < n) deg[idx] = 1;
    if (idx < NFEAT * 128) {
        int k = idx >> 7, c = idx & 127;
        W1T[(size_t)c * NFEAT + k] = f2b(W1[idx]);
    } else {
        int j = idx - NFEAT * 128;
        if (j < NHID * 128) {
            int k = j >> 7, c = j & 127;
            W2T[(size_t)c * NHID + k] = f2b(W2[j]);
        }
    }
}

// count + ticket: atomic return value = slot index within node (1-based; self-loop base 1)
__global__ void k_count(const int* __restrict__ dst, int e, int* __restrict__ deg,
                        int* __restrict__ ticket) {
    int i = blockIdx.x * blockDim.x + threadIdx.x;
    if (i < e) ticket[i] = atomicAdd(&deg[dst[i]], 1);
}

// scan deg (edge offsets, no padding) fused with dinv init
__global__ void k_scan1(const int* __restrict__ deg, float* __restrict__ dinv,
                        int* __restrict__ offs, int* __restrict__ bsum, int n) {
    __shared__ int s[SCAN_BS];
    int t = threadIdx.x;
    int i = blockIdx.x * SCAN_BS + t;
    int d = (i < n) ? deg[i] : 0;
    if (i < n) dinv[i] = rsqrtf((float)d);
    s[t] = d;
    for (int off = 1; off < SCAN_BS; off <<= 1) {
        __syncthreads();
        int x = (t >= off) ? s[t - off] : 0;
        __syncthreads();
        s[t] += x;
    }
    __syncthreads();
    if (i < n) offs[i] = s[t] - d;
    if (t == SCAN_BS - 1) bsum[blockIdx.x] = s[t];
}

// scan3 with scan2 folded in: every block re-scans the (<=128) block sums itself
__global__ void k_scan3(int* __restrict__ offs, const int* __restrict__ bsum, int nb, int n) {
    __shared__ int pref[128];
    int t = threadIdx.x;
    if (t < 64) {
        int carry = 0;
        for (int base = 0; base < nb; base += 64) {
            int j = base + t;
            int v = (j < nb) ? bsum[j] : 0;
            for (int off = 1; off < 64; off <<= 1) {
                int x = __shfl_up(v, off);
                if (t >= off) v += x;
            }
            if (j < nb) pref[j] = carry + v;   // inclusive prefix
            carry += __shfl(v, 63);
        }
    }
    __syncthreads();
    int i = blockIdx.x * SCAN_BS + t;
    int add = blockIdx.x ? pref[blockIdx.x - 1] : 0;
    if (i < n) offs[i] += add;
    if (blockIdx.x == 0 && t == 0) offs[n] = pref[nb - 1];   // = S
}

// atomic-free edge scatter + self/meta slot + pad words + stream-start table
// colp32[slot] = src(16b) | meta(16b); meta = dst+1 on the LAST slot (self-loop) of each node.
__global__ void k_fill_edges(const int* __restrict__ src, const int* __restrict__ dst, int e,
                             const int* __restrict__ eoffs, const int* __restrict__ ticket,
                             uint* __restrict__ colp32, int* __restrict__ rankgs,
                             int n, int S) {
    int i = blockIdx.x * blockDim.x + threadIdx.x;
    if (i < e) {
        colp32[eoffs[dst[i]] + ticket[i] - 1] = (uint)src[i];   // meta 0
    }
    if (i < n) {
        colp32[eoffs[i + 1] - 1] = (uint)i | ((uint)(i + 1) << 16);  // self-loop + boundary meta
    }
    if (i < NSTREAMS) {
        int len = (S + NSTREAMS - 1) / NSTREAMS;
        int target = i * len;
        int lo = 0, hi = n;                       // eoffs[n] = S
        while (lo < hi) {                         // lower_bound: first eoffs[v] >= target
            int mid = (lo + hi) >> 1;
            if (eoffs[mid] < target) lo = mid + 1; else hi = mid;
        }
        rankgs[i] = eoffs[lo];
        if (i == 0) rankgs[NSTREAMS] = S;
    }
    if (i == 0) {
#pragma unroll
        for (int k = 0; k < 8; k++) colp32[S + k] = 0;   // prefetch pad (src 0, no meta)
    }
}

// ---------------- bf16 MFMA GEMM, 64x128 tile -> 4-slice output ----------------
// 4 waves; wave wc owns output cols [wc*32, wc*32+32) = slice wc.
// Hs layout: [slice(4)][node(M)][32 feats] bf16, pre-scaled by rowscale[row].

template<int A_F32>
__global__ __launch_bounds__(256) void k_gemm(const void* __restrict__ Aptr,
                                              const ushort* __restrict__ WT,
                                              const float* __restrict__ rowscale,
                                              ushort* __restrict__ Hs, int M, int K) {
    __shared__ ushort As[64][40];   // pad 40: <=2-way bank conflict (free)
    __shared__ ushort Bs[128][40];

    const int tid = threadIdx.x;
    const int wc = tid >> 6, lane = tid & 63;
    const int lr = lane & 15, lk = (lane >> 4) * 8;
    const int rowbase = blockIdx.x * 64;

    f32x4 acc[4][2];
#pragma unroll
    for (int i = 0; i < 4; i++)
#pragma unroll
        for (int j = 0; j < 2; j++) acc[i][j] = (f32x4)0.f;

    const int sr = tid >> 2;        // staging row 0..63
    const int sh = (tid & 3) * 8;   // staging octet

    for (int k0 = 0; k0 < K; k0 += 32) {
        {
            int gr = rowbase + sr;
            ushort tmp[8];
            if (A_F32) {
                const float* A = (const float*)Aptr;
                if (gr < M) {
                    const float* p = A + (size_t)gr * K + k0 + sh;
#pragma unroll
                    for (int q = 0; q < 2; q++) {
                        float4 v = *(const float4*)(p + q * 4);
                        tmp[q * 4 + 0] = f2b(v.x); tmp[q * 4 + 1] = f2b(v.y);
                        tmp[q * 4 + 2] = f2b(v.z); tmp[q * 4 + 3] = f2b(v.w);
                    }
                } else {
#pragma unroll
                    for (int q = 0; q < 8; q++) tmp[q] = 0;
                }
            } else {
                const ushort* A = (const ushort*)Aptr;
                if (gr < M) {
                    *(short8*)&tmp[0] = *(const short8*)(A + (size_t)gr * K + k0 + sh);
                } else {
#pragma unroll
                    for (int q = 0; q < 8; q++) tmp[q] = 0;
                }
            }
            *(short8*)&As[sr][sh] = *(short8*)&tmp[0];
        }
        {
#pragma unroll
            for (int t = 0; t < 2; t++) {
                int c = tid + t * 256;
                int row = c >> 2, q = c & 3;
                short8 v = *(const short8*)(WT + (size_t)row * K + k0 + q * 8);
                *(short8*)&Bs[row][q * 8] = v;
            }
        }
        __syncthreads();

        short8 af[4], bfv[2];
#pragma unroll
        for (int i = 0; i < 4; i++) af[i] = *(const short8*)&As[i * 16 + lr][lk];
#pragma unroll
        for (int j = 0; j < 2; j++) bfv[j] = *(const short8*)&Bs[wc * 32 + j * 16 + lr][lk];
#pragma unroll
        for (int i = 0; i < 4; i++)
#pragma unroll
            for (int j = 0; j < 2; j++)
                acc[i][j] = __builtin_amdgcn_mfma_f32_16x16x32_bf16(af[i], bfv[j], acc[i][j], 0, 0, 0);
        __syncthreads();
    }

#pragma unroll
    for (int i = 0; i < 4; i++) {
#pragma unroll
        for (int r = 0; r < 4; r++) {
            int row = rowbase + i * 16 + (lane >> 4) * 4 + r;
            if (row < M) {
                float sc = rowscale[row];
#pragma unroll
                for (int j = 0; j < 2; j++) {
                    int f = j * 16 + lr;
                    Hs[((size_t)wc * M + row) * 32 + f] = f2b(acc[i][j][r] * sc);
                }
            }
        }
    }
}

// ---------------- stream-parallel segmented aggregation, depth-4 pipeline ----------------
// 16 streams per wave (4 lanes x 16B each); stream owns exact node range
// [rankgs[r], rankgs[r+1]); flush at node boundary (meta word), no cross-lane reduce.

__global__ __launch_bounds__(256) void k_aggs(const ushort* __restrict__ hs,
                                              const uint* __restrict__ colp32,
                                              const int* __restrict__ rankgs,
                                              const float* __restrict__ dinv,
                                              const float* __restrict__ bias,
                                              ushort* __restrict__ outp, int n) {
    const int b = blockIdx.x;
    const int s = b & 3;                          // slice, pinned to XCDs {s, s+4}
    const int wid = threadIdx.x >> 6, lane = threadIdx.x & 63;
    const int st16 = lane >> 2, q = lane & 3;     // stream-in-wave, feat-quad (16B)
    const int stream = (((b >> 2) << 2) + wid) * 16 + st16;
    int gs = rankgs[stream];
    int se = rankgs[stream + 1];
    bool alive = gs < se;
    int g = gs;

    const ushort* hsl = hs + (size_t)s * n * 32;
    const float4 bv0 = *(const float4*)(bias + s * 32 + q * 8);
    const float4 bv1 = *(const float4*)(bias + s * 32 + q * 8 + 4);

    const uint* cp = colp32 + g;
    uint cw0 = cp[0], cw1 = cp[1], cw2 = cp[2], cw3 = cp[3];
    uint4 pk0 = *(const uint4*)(hsl + (size_t)(cw0 & 0xffffu) * 32 + q * 8);
    uint4 pk1 = *(const uint4*)(hsl + (size_t)(cw1 & 0xffffu) * 32 + q * 8);
    uint4 pk2 = *(const uint4*)(hsl + (size_t)(cw2 & 0xffffu) * 32 + q * 8);
    float fdv0 = (cw0 >> 16) ? dinv[(cw0 >> 16) - 1] : 0.f;
    float fdv1 = (cw1 >> 16) ? dinv[(cw1 >> 16) - 1] : 0.f;
    float fdv2 = (cw2 >> 16) ? dinv[(cw2 >> 16) - 1] : 0.f;
    float a0 = 0.f, a1 = 0.f, a2 = 0.f, a3 = 0.f;
    float a4 = 0.f, a5 = 0.f, a6 = 0.f, a7 = 0.f;

    while (__any(alive)) {
        if (alive) {
            uint cw4 = cp[4];
            uint4 pk3 = *(const uint4*)(hsl + (size_t)(cw3 & 0xffffu) * 32 + q * 8);
            float fdv3 = (cw3 >> 16) ? dinv[(cw3 >> 16) - 1] : 0.f;

            a0 += b2f_lo(pk0.x); a1 += b2f_hi(pk0.x);
            a2 += b2f_lo(pk0.y); a3 += b2f_hi(pk0.y);
            a4 += b2f_lo(pk0.z); a5 += b2f_hi(pk0.z);
            a6 += b2f_lo(pk0.w); a7 += b2f_hi(pk0.w);

            if (cw0 >> 16) {   // node boundary (per-stream, exec-masked)
                int v = (int)(cw0 >> 16) - 1;
                float r0 = fmaxf(fmaf(a0, fdv0, bv0.x), 0.f);
                float r1 = fmaxf(fmaf(a1, fdv0, bv0.y), 0.f);
                float r2 = fmaxf(fmaf(a2, fdv0, bv0.z), 0.f);
                float r3 = fmaxf(fmaf(a3, fdv0, bv0.w), 0.f);
                float r4 = fmaxf(fmaf(a4, fdv0, bv1.x), 0.f);
                float r5 = fmaxf(fmaf(a5, fdv0, bv1.y), 0.f);
                float r6 = fmaxf(fmaf(a6, fdv0, bv1.z), 0.f);
                float r7 = fmaxf(fmaf(a7, fdv0, bv1.w), 0.f);
                uint4 u;
                u.x = (uint)f2b(r0) | ((uint)f2b(r1) << 16);
                u.y = (uint)f2b(r2) | ((uint)f2b(r3) << 16);
                u.z = (uint)f2b(r4) | ((uint)f2b(r5) << 16);
                u.w = (uint)f2b(r6) | ((uint)f2b(r7) << 16);
                *(uint4*)(outp + (size_t)v * 128 + s * 32 + q * 8) = u;
                a0 = a1 = a2 = a3 = a4 = a5 = a6 = a7 = 0.f;
                if (g + 1 >= se) alive = false;
            }
            g++; cp++;
            cw0 = cw1; cw1 = cw2; cw2 = cw3; cw3 = cw4;
            pk0 = pk1; pk1 = pk2; pk2 = pk3;
            fdv0 = fdv1; fdv1 = fdv2; fdv2 = fdv3;
        }
    }
}

// ---------------- classifier + log_softmax (bf16 hidden input, row-major) ----------------

__global__ __launch_bounds__(256) void k_classify(const ushort* __restrict__ h,
                                                  const float* __restrict__ Wc,
                                                  const float* __restrict__ bc,
                                                  float* __restrict__ out, int n) {
    __shared__ float Ws[128 * 16];
    int tid = threadIdx.x;
#pragma unroll
    for (int t = 0; t < 8; t++) Ws[tid + 256 * t] = Wc[tid + 256 * t];
    __syncthreads();

    int wid = tid >> 6, lane = tid & 63;
    int v = blockIdx.x * 4 + wid;
    if (v >= n) return;

    int j = lane & 15, c = lane >> 4;
    const ushort* hv = h + (size_t)v * 128 + c * 32;
    float acc = 0.f;
#pragma unroll
    for (int t = 0; t < 16; t++) {
        uint pk = *(const uint*)(hv + t * 2);
        acc = fmaf(b2f_lo(pk), Ws[(c * 32 + t * 2 + 0) * 16 + j], acc);
        acc = fmaf(b2f_hi(pk), Ws[(c * 32 + t * 2 + 1) * 16 + j], acc);
    }
    acc += __shfl_xor(acc, 16);
    acc += __shfl_xor(acc, 32);
    acc += bc[j];

    float m = acc;
#pragma unroll
    for (int o = 8; o >= 1; o >>= 1) m = fmaxf(m, __shfl_xor(m, o));
    float sum = expf(acc - m);
#pragma unroll
    for (int o = 8; o >= 1; o >>= 1) sum += __shfl_xor(sum, o);
    if (lane < 16) out[(size_t)v * 16 + j] = acc - m - logf(sum);
}

// ---------------- launch ----------------

extern "C" void kernel_launch(void* const* d_in, const int* in_sizes, int n_in,
                              void* d_out, int out_size, void* d_ws, size_t ws_size,
                              hipStream_t stream) {
    const float* x  = (const float*)d_in[0];
    const int* eidx = (const int*)d_in[1];
    const float* W1 = (const float*)d_in[2];
    const float* b1 = (const float*)d_in[3];
    const float* W2 = (const float*)d_in[4];
    const float* b2 = (const float*)d_in[5];
    const float* Wc = (const float*)d_in[6];
    const float* bc = (const float*)d_in[7];
    float* out = (float*)d_out;

    const int N = in_sizes[0] / NFEAT;   // 50000 (< 65536 -> 16-bit node ids)
    const int E = in_sizes[1] / 2;       // 800000
    const int S = E + N;                 // total slots (no padding)
    const int* src = eidx;
    const int* dst = eidx + E;

    char* p = (char*)d_ws;
    auto alloc = [&](size_t bytes) { char* r = p; p += (bytes + 255) & ~(size_t)255; return r; };
    int*    deg    = (int*)   alloc((size_t)N * 4);
    float*  dinv   = (float*) alloc((size_t)N * 4);
    int*    eoffs  = (int*)   alloc((size_t)(N + 1) * 4);
    int*    ticket = (int*)   alloc((size_t)E * 4);
    uint*   colp32 = (uint*)  alloc(((size_t)S + 16) * 4);
    int*    rankgs = (int*)   alloc((size_t)(NSTREAMS + 1) * 4);
    int*    bsum   = (int*)   alloc((size_t)256 * 4);
    ushort* W1T    = (ushort*)alloc((size_t)128 * NFEAT * 2);
    ushort* W2T    = (ushort*)alloc((size_t)128 * NHID * 2);
    ushort* hs     = (ushort*)alloc((size_t)N * NHID * 2);   // 4 slices x N x 32
    ushort* g1     = (ushort*)alloc((size_t)N * NHID * 2);   // agg1 out, row-major bf16
    ushort* g2     = (ushort*)alloc((size_t)N * NHID * 2);   // agg2 out, row-major bf16

    const int nb = (N + SCAN_BS - 1) / SCAN_BS;

    k_init_tcast<<<((NFEAT + NHID) * 128 + 255) / 256, 256, 0, stream>>>(W1, W2, W1T, W2T, deg, N);
    k_count<<<(E + 255) / 256, 256, 0, stream>>>(dst, E, deg, ticket);
    k_scan1<<<nb, SCAN_BS, 0, stream>>>(deg, dinv, eoffs, bsum, N);
    k_scan3<<<nb, SCAN_BS, 0, stream>>>(eoffs, bsum, nb, N);
    k_fill_edges<<<(E + 255) / 256, 256, 0, stream>>>(src, dst, E, eoffs, ticket, colp32,
                                                      rankgs, N, S);

    const int gblocks = (N + 63) / 64;
    // layer 1
    k_gemm<1><<<gblocks, 256, 0, stream>>>(x, W1T, dinv, hs, N, NFEAT);
    k_aggs<<<AGG_BLOCKS, 256, 0, stream>>>(hs, colp32, rankgs, dinv, b1, g1, N);
    // layer 2
    k_gemm<0><<<gblocks, 256, 0, stream>>>(g1, W2T, dinv, hs, N, NHID);
    k_aggs<<<AGG_BLOCKS, 256, 0, stream>>>(hs, colp32, rankgs, dinv, b2, g2, N);
    // classifier
    k_classify<<<(N + 3) / 4, 256, 0, stream>>>(g2, Wc, bc, out, N);
}